// Round 1
// baseline (400.749 us; speedup 1.0000x reference)
//
#include <hip/hip_runtime.h>

typedef __attribute__((ext_vector_type(8))) short short8;
typedef __attribute__((ext_vector_type(4))) float floatx4;

#define N_ROWS 65536
#define K_CB   1024
#define D_DIM  256

// 2-term split (ah*bh + al*bh): W's bf16 residual is dropped; its error
// (sigma ~2-3e-5 on distances) is folded into a wider recheck band.
#define TAU 3.0e-4f
#define BLINE 520   // shorts per B LDS line (512 data + 8 pad = 1040 B; staggers banks by 4/line)

// ws layout (bytes) — ~1.4 MB, ws_size >= 14 MB proven on this harness
#define OFF_RN     0         // float[65536]
#define OFF_WN     262144    // float[1024]
#define OFF_FIXCNT 266240    // int
#define OFF_HIST   266496    // int[1024]
#define OFF_IDX    270592    // int[65536]
#define OFF_LIST   532736    // int[65536]
#define OFF_PART   794880    // double[4096]
#define OFF_WFRAG  827392    // ushort[32*1024*8] = 512 KB (hi fragments only)

// ---- numpy pairwise fp32 sum-of-squares emulation (contract off!) ----
__device__ __forceinline__ float pw128_sq(const float4* p) {
#pragma clang fp contract(off)
    float4 q0 = p[0], q1 = p[1];
    float r0 = q0.x * q0.x, r1 = q0.y * q0.y, r2 = q0.z * q0.z, r3 = q0.w * q0.w;
    float r4 = q1.x * q1.x, r5 = q1.y * q1.y, r6 = q1.z * q1.z, r7 = q1.w * q1.w;
    for (int i = 1; i < 16; ++i) {
        float4 u0 = p[2 * i], u1 = p[2 * i + 1];
        r0 = r0 + u0.x * u0.x; r1 = r1 + u0.y * u0.y;
        r2 = r2 + u0.z * u0.z; r3 = r3 + u0.w * u0.w;
        r4 = r4 + u1.x * u1.x; r5 = r5 + u1.y * u1.y;
        r6 = r6 + u1.z * u1.z; r7 = r7 + u1.w * u1.w;
    }
    return ((r0 + r1) + (r2 + r3)) + ((r4 + r5) + (r6 + r7));
}
__device__ __forceinline__ float rownorm_np(const float* row) {
#pragma clang fp contract(off)
    float s0 = pw128_sq((const float4*)row);
    float s1 = pw128_sq((const float4*)(row + 128));
    return s0 + s1;
}
__device__ __forceinline__ float np_dist(float A, float m, float Ck) {
#pragma clang fp contract(off)
    float Bv = 2.0f * m;
    float t  = A - Bv;
    return t + Ck;
}
__device__ __forceinline__ unsigned short bf16_rne(float x) {
    unsigned u = __float_as_uint(x);
    unsigned r = u + 0x7fff + ((u >> 16) & 1);
    return (unsigned short)(r >> 16);
}
__device__ __forceinline__ float bf16_tof(unsigned short h) {
    return __uint_as_float(((unsigned)h) << 16);
}

// ---------------- K1: fused prep — e-norms (coalesced) + w-norms + wfrag ----------------
#define PRS 260
__global__ __launch_bounds__(256) void k_prep(
        const float* __restrict__ eg, const float* __restrict__ wg,
        float* __restrict__ rn, float* __restrict__ wn,
        unsigned short* __restrict__ wfrag) {
    __shared__ __align__(16) float es[32 * PRS];
    const int tid = threadIdx.x;
    const int bx  = blockIdx.x;
    if (bx < 2048) {
        // ---- e-norms: 32 rows, LDS-staged coalesced ----
        const int rowBase = bx * 32;
        #pragma unroll
        for (int j = 0; j < 8; ++j) {
            int f4 = j * 256 + tid;
            int row = f4 >> 6, k4 = f4 & 63;
            float4 v = *(const float4*)(eg + (size_t)(rowBase + row) * D_DIM + k4 * 4);
            *(float4*)&es[row * PRS + k4 * 4] = v;
        }
        __syncthreads();
        if (tid < 64) {
            int row = tid >> 1, half = tid & 1;
            float s = pw128_sq((const float4*)&es[row * PRS + half * 128]);
            float so = __shfl_xor(s, 1, 64);
            if (half == 0) rn[rowBase + row] = s + so;
        }
    } else if (bx < 2052) {
        // ---- w-norms: thread-per-row (1024 rows total) ----
        int row = (bx - 2048) * 256 + tid;
        wn[row] = rownorm_np(wg + (size_t)row * D_DIM);
    } else {
        // ---- wfrag: bf16-hi fragments only, layout [kc][col][8] ----
        int t = (bx - 2052) * 256 + tid;     // 0..32767
        int col = t >> 5, kc = t & 31;
        const float4* src = (const float4*)(wg + (size_t)col * D_DIM + kc * 8);
        float4 v0 = src[0], v1 = src[1];
        const float a[8] = {v0.x, v0.y, v0.z, v0.w, v1.x, v1.y, v1.z, v1.w};
        short8 h;
        #pragma unroll
        for (int i = 0; i < 8; ++i) h[i] = (short)bf16_rne(a[i]);
        *(short8*)(wfrag + ((size_t)kc * 1024 + col) * 8) = h;
    }
}

// ---------------- K2: MFMA split-2 distance — A in registers, full col sweep ----------------
// grid(512): block = 128 rows; wave = 32 rows (2 mt); 16 col-phases of 64 codes
// terms: ah*bh + al*bh  (W-lo dropped; TAU widened to cover)
__global__ __launch_bounds__(256, 2) void k_dist(
        const float* __restrict__ eg, const unsigned short* __restrict__ wfrag,
        const float* __restrict__ rn, const float* __restrict__ wn,
        int* __restrict__ idx_ws, int* __restrict__ fixlist, int* __restrict__ fixcnt) {
    __shared__ __align__(16) unsigned short Bs[32 * BLINE];
    const int tid  = threadIdx.x;
    const int lane = tid & 63;
    const int wv   = tid >> 6;
    const int q    = lane >> 4;
    const int m15  = lane & 15;
    const int waveRow = blockIdx.x * 128 + wv * 32;

    // ---- A fragments: load fp32, split hi/lo, keep in registers for whole kernel ----
    short8 afh[2][8], afl[2][8];
    #pragma unroll
    for (int mt = 0; mt < 2; ++mt) {
        const float* rowp = eg + (size_t)(waveRow + mt * 16 + m15) * D_DIM + q * 8;
        #pragma unroll
        for (int win = 0; win < 8; ++win) {
            const float4* pa = (const float4*)(rowp + win * 32);
            float4 x0 = pa[0], x1 = pa[1];
            const float a[8] = {x0.x, x0.y, x0.z, x0.w, x1.x, x1.y, x1.z, x1.w};
            short8 h, l;
            #pragma unroll
            for (int i = 0; i < 8; ++i) {
                unsigned short hh = bf16_rne(a[i]);
                h[i] = (short)hh;
                l[i] = (short)bf16_rne(a[i] - bf16_tof(hh));
            }
            afh[mt][win] = h;
            afl[mt][win] = l;
        }
    }
    // row norms for this lane's 8 C-row slots (row = mt*16 + q*4 + reg)
    float rnv[8];
    #pragma unroll
    for (int mt = 0; mt < 2; ++mt)
        #pragma unroll
        for (int reg = 0; reg < 4; ++reg)
            rnv[mt * 4 + reg] = rn[waveRow + mt * 16 + q * 4 + reg];

    float best[8], sec[8];
    int bidx[8];
    #pragma unroll
    for (int s = 0; s < 8; ++s) { best[s] = 3.4e38f; sec[s] = 3.4e38f; bidx[s] = 0; }

    for (int cb = 0; cb < 16; ++cb) {
        __syncthreads();   // Bs reuse guard
        // stage this phase's B tile: 32 lines of 1 KB via global_load_lds, 8 lines/wave
        #pragma unroll
        for (int t = 0; t < 8; ++t) {
            int L = wv * 8 + t;   // = kc 0..31
            const unsigned short* src = wfrag + ((size_t)L * 1024 + cb * 64) * 8 + lane * 8;
            __builtin_amdgcn_global_load_lds(
                (const __attribute__((address_space(1))) unsigned int*)src,
                (__attribute__((address_space(3))) unsigned int*)&Bs[L * BLINE],
                16, 0, 0);
        }
        __syncthreads();   // compiler emits vmcnt(0) drain before barrier

        floatx4 acc[2][4];
        #pragma unroll
        for (int mt = 0; mt < 2; ++mt)
            #pragma unroll
            for (int nt = 0; nt < 4; ++nt)
                acc[mt][nt] = (floatx4){0.f, 0.f, 0.f, 0.f};

        #pragma unroll
        for (int nt = 0; nt < 4; ++nt) {
            #pragma unroll
            for (int win = 0; win < 8; ++win) {
                int kc = win * 4 + q;
                short8 bfh = *(short8*)&Bs[kc * BLINE + (nt * 16 + m15) * 8];
                acc[0][nt] = __builtin_amdgcn_mfma_f32_16x16x32_bf16(afh[0][win], bfh, acc[0][nt], 0, 0, 0);
                acc[0][nt] = __builtin_amdgcn_mfma_f32_16x16x32_bf16(afl[0][win], bfh, acc[0][nt], 0, 0, 0);
                acc[1][nt] = __builtin_amdgcn_mfma_f32_16x16x32_bf16(afh[1][win], bfh, acc[1][nt], 0, 0, 0);
                acc[1][nt] = __builtin_amdgcn_mfma_f32_16x16x32_bf16(afl[1][win], bfh, acc[1][nt], 0, 0, 0);
            }
        }
        // fold distances into running top-2 (cols ascend with cb,nt -> first-min kept)
        #pragma unroll
        for (int nt = 0; nt < 4; ++nt) {
            int col = cb * 64 + nt * 16 + m15;
            float Ck = wn[col];
            #pragma unroll
            for (int mt = 0; mt < 2; ++mt)
                #pragma unroll
                for (int reg = 0; reg < 4; ++reg) {
                    int s = mt * 4 + reg;
                    float d = np_dist(rnv[s], acc[mt][nt][reg], Ck);
                    if (d < best[s])     { sec[s] = best[s]; best[s] = d; bidx[s] = col; }
                    else if (d < sec[s]) { sec[s] = d; }
                }
        }
    }

    // butterfly top-2 merge across the 16 m15 lanes (rows live per (q,mt,reg))
    #pragma unroll
    for (int s = 0; s < 8; ++s) {
        float b = best[s], se = sec[s];
        int ix = bidx[s];
        #pragma unroll
        for (int m = 1; m < 16; m <<= 1) {
            float bo = __shfl_xor(b, m, 64);
            float so = __shfl_xor(se, m, 64);
            int   io = __shfl_xor(ix, m, 64);
            float ns = fminf(fminf(se, so), fmaxf(b, bo));
            if (bo < b || (bo == b && io < ix)) { b = bo; ix = io; }
            se = ns;
        }
        if (m15 == 0) {
            int row = waveRow + (s >> 2) * 16 + q * 4 + (s & 3);
            idx_ws[row] = ix;
            if (se - b < TAU) {
                int p = atomicAdd(fixcnt, 1);
                fixlist[p] = row;
            }
        }
    }
}

// ---------------- K3: fp64 np-exact recheck, 4 flagged rows share each w sweep ----------------
__global__ void k_fixup(const float* __restrict__ eg, const float* __restrict__ wg,
                        const float* __restrict__ rn, const float* __restrict__ wnorm,
                        const int* __restrict__ fixlist, const int* __restrict__ fixcnt,
                        int* __restrict__ idx_ws) {
    __shared__ double xs[4][D_DIM];
    __shared__ float  redv[256];
    __shared__ int    redi[256];
    const int tid = threadIdx.x;
    const int cnt = *fixcnt;
    const int ngroups = (cnt + 3) >> 2;
    for (int g = blockIdx.x; g < ngroups; g += gridDim.x) {
        __syncthreads();
        int rows[4];
        #pragma unroll
        for (int i = 0; i < 4; ++i) {
            int j = g * 4 + i;
            rows[i] = fixlist[j < cnt ? j : cnt - 1];
        }
        #pragma unroll
        for (int i = 0; i < 4; ++i)
            xs[i][tid] = (double)eg[(size_t)rows[i] * D_DIM + tid];
        __syncthreads();
        float An[4];
        #pragma unroll
        for (int i = 0; i < 4; ++i) An[i] = rn[rows[i]];
        float bestv[4] = {3.4e38f, 3.4e38f, 3.4e38f, 3.4e38f};
        int   besti[4] = {0, 0, 0, 0};
        #pragma unroll
        for (int kk = 0; kk < 4; ++kk) {
            int k = tid + kk * 256;
            const float4* wr = (const float4*)(wg + (size_t)k * D_DIM);
            double s0 = 0.0, s1 = 0.0, s2 = 0.0, s3 = 0.0;
            for (int i = 0; i < D_DIM / 4; ++i) {
                float4 f = wr[i];
                double f0 = f.x, f1 = f.y, f2 = f.z, f3 = f.w;
                s0 += xs[0][4*i] * f0 + xs[0][4*i+1] * f1 + xs[0][4*i+2] * f2 + xs[0][4*i+3] * f3;
                s1 += xs[1][4*i] * f0 + xs[1][4*i+1] * f1 + xs[1][4*i+2] * f2 + xs[1][4*i+3] * f3;
                s2 += xs[2][4*i] * f0 + xs[2][4*i+1] * f1 + xs[2][4*i+2] * f2 + xs[2][4*i+3] * f3;
                s3 += xs[3][4*i] * f0 + xs[3][4*i+1] * f1 + xs[3][4*i+2] * f2 + xs[3][4*i+3] * f3;
            }
            const double ss[4] = {s0, s1, s2, s3};
            float Cw = wnorm[k];
            #pragma unroll
            for (int i = 0; i < 4; ++i) {
                float d = np_dist(An[i], (float)ss[i], Cw);
                if (d < bestv[i]) { bestv[i] = d; besti[i] = k; }
            }
        }
        #pragma unroll
        for (int i = 0; i < 4; ++i) {
            __syncthreads();
            redv[tid] = bestv[i]; redi[tid] = besti[i];
            __syncthreads();
            for (int st = 128; st > 0; st >>= 1) {
                if (tid < st) {
                    float ov = redv[tid + st]; int oi = redi[tid + st];
                    if (ov < redv[tid] || (ov == redv[tid] && oi < redi[tid])) {
                        redv[tid] = ov; redi[tid] = oi;
                    }
                }
                __syncthreads();
            }
            if (tid == 0 && g * 4 + i < cnt) idx_ws[rows[i]] = redi[0];
        }
    }
}

// ---------------- K4: gather + STE + loss partials + histogram (float4 vectorized) ----------------
__global__ void k_final(const float* __restrict__ eg, const float* __restrict__ wg,
                        const int* __restrict__ idx_ws, float* __restrict__ qout,
                        float* __restrict__ iout, int* __restrict__ hist,
                        double* __restrict__ partials) {
    const int tid  = threadIdx.x;
    const int sub  = tid >> 6;      // 0..3: row within quad
    const int lane = tid & 63;      // float4 column
    const int rowBase = blockIdx.x * 16;
    double acc = 0.0;
    #pragma unroll
    for (int g = 0; g < 4; ++g) {
        int row = rowBase + g * 4 + sub;
        int k = idx_ws[row];
        float4 ev = ((const float4*)(eg + (size_t)row * D_DIM))[lane];
        float4 wv = ((const float4*)(wg + (size_t)k   * D_DIM))[lane];
        float dx = wv.x - ev.x, dy = wv.y - ev.y, dz = wv.z - ev.z, dw = wv.w - ev.w;
        float4 qv = {ev.x + dx, ev.y + dy, ev.z + dz, ev.w + dw};
        ((float4*)(qout + (size_t)row * D_DIM))[lane] = qv;
        acc += (double)(dx * dx) + (double)(dy * dy)
             + (double)(dz * dz) + (double)(dw * dw);
        if (lane == 0) {
            iout[row] = (float)k;
            atomicAdd(&hist[k], 1);
        }
    }
    __shared__ double red[256];
    red[tid] = acc;
    __syncthreads();
    for (int st = 128; st > 0; st >>= 1) {
        if (tid < st) red[tid] += red[tid + st];
        __syncthreads();
    }
    if (tid == 0) partials[blockIdx.x] = red[0];
}

// ---------------- K5: scalars ----------------
__global__ void k_scalars(const int* __restrict__ hist, const double* __restrict__ partials,
                          float* __restrict__ sout) {
    const int tid = threadIdx.x;
    double s = 0.0;
    for (int j = tid; j < N_ROWS / 16; j += 256) s += partials[j];
    int m = 0;
    for (int j = tid; j < K_CB; j += 256) m = max(m, hist[j]);
    __shared__ double rs[256];
    __shared__ int    rm[256];
    rs[tid] = s; rm[tid] = m;
    __syncthreads();
    for (int st = 128; st > 0; st >>= 1) {
        if (tid < st) { rs[tid] += rs[tid + st]; rm[tid] = max(rm[tid], rm[tid + st]); }
        __syncthreads();
    }
    if (tid == 0) {
        sout[0] = (float)(rs[0] / (double)((size_t)N_ROWS * D_DIM));
        sout[1] = (float)rm[0] / 65536.0f;
    }
}

extern "C" void kernel_launch(void* const* d_in, const int* in_sizes, int n_in,
                              void* d_out, int out_size, void* d_ws, size_t ws_size,
                              hipStream_t stream) {
    const float* e = (const float*)d_in[0];
    const float* w = (const float*)d_in[1];
    float* out  = (float*)d_out;
    float* qout = out;
    float* iout = out + (size_t)N_ROWS * D_DIM;
    float* sout = iout + N_ROWS;

    char* ws = (char*)d_ws;
    float*  rn       = (float*) (ws + OFF_RN);
    float*  wn       = (float*) (ws + OFF_WN);
    int*    fixcnt   = (int*)   (ws + OFF_FIXCNT);
    int*    hist     = (int*)   (ws + OFF_HIST);
    int*    idxp     = (int*)   (ws + OFF_IDX);
    int*    list     = (int*)   (ws + OFF_LIST);
    double* partials = (double*)(ws + OFF_PART);
    unsigned short* wfrag = (unsigned short*)(ws + OFF_WFRAG);

    hipMemsetAsync(ws + OFF_FIXCNT, 0, 4352, stream);   // fixcnt + hist

    hipLaunchKernelGGL(k_prep,    dim3(2180),         dim3(256), 0, stream, e, w, rn, wn, wfrag);
    hipLaunchKernelGGL(k_dist,    dim3(512),          dim3(256), 0, stream, e, wfrag, rn, wn, idxp, list, fixcnt);
    hipLaunchKernelGGL(k_fixup,   dim3(512),          dim3(256), 0, stream, e, w, rn, wn, list, fixcnt, idxp);
    hipLaunchKernelGGL(k_final,   dim3(N_ROWS / 16),  dim3(256), 0, stream, e, w, idxp, qout, iout, hist, partials);
    hipLaunchKernelGGL(k_scalars, dim3(1),            dim3(256), 0, stream, hist, partials, sout);
}

// Round 2
// 373.425 us; speedup vs baseline: 1.0732x; 1.0732x over previous
//
#include <hip/hip_runtime.h>

typedef __attribute__((ext_vector_type(8))) short short8;
typedef __attribute__((ext_vector_type(4))) float floatx4;

#define N_ROWS 65536
#define K_CB   1024
#define D_DIM  256

// 2-term split (ah*bh + al*bh): W's bf16 residual is dropped; its error
// (sigma ~2-3e-5 on distances) is folded into a wider recheck band.
#define TAU 3.0e-4f
#define BLINE 520   // shorts per B LDS line (512 data + 8 pad = 1040 B; staggers banks by 4/line)

// ws layout (bytes) — ~1.9 MB, ws_size >= 14 MB proven on this harness
#define OFF_RN     0         // float[65536]
#define OFF_WN     262144    // float[1024]
#define OFF_FIXCNT 266240    // int
#define OFF_HIST   266496    // int[1024]
#define OFF_IDX    270592    // int[65536]
#define OFF_LIST   532736    // int[65536]
#define OFF_PART   794880    // double[4096]
#define OFF_WFRAG  827392    // ushort[32*1024*8] = 512 KB (hi fragments only)
#define OFF_KEYS   1351680   // u64[65536] = 512 KB (fixup argmin keys)

// ---- numpy pairwise fp32 sum-of-squares emulation (contract off!) ----
__device__ __forceinline__ float pw128_sq(const float4* p) {
#pragma clang fp contract(off)
    float4 q0 = p[0], q1 = p[1];
    float r0 = q0.x * q0.x, r1 = q0.y * q0.y, r2 = q0.z * q0.z, r3 = q0.w * q0.w;
    float r4 = q1.x * q1.x, r5 = q1.y * q1.y, r6 = q1.z * q1.z, r7 = q1.w * q1.w;
    for (int i = 1; i < 16; ++i) {
        float4 u0 = p[2 * i], u1 = p[2 * i + 1];
        r0 = r0 + u0.x * u0.x; r1 = r1 + u0.y * u0.y;
        r2 = r2 + u0.z * u0.z; r3 = r3 + u0.w * u0.w;
        r4 = r4 + u1.x * u1.x; r5 = r5 + u1.y * u1.y;
        r6 = r6 + u1.z * u1.z; r7 = r7 + u1.w * u1.w;
    }
    return ((r0 + r1) + (r2 + r3)) + ((r4 + r5) + (r6 + r7));
}
__device__ __forceinline__ float rownorm_np(const float* row) {
#pragma clang fp contract(off)
    float s0 = pw128_sq((const float4*)row);
    float s1 = pw128_sq((const float4*)(row + 128));
    return s0 + s1;
}
__device__ __forceinline__ float np_dist(float A, float m, float Ck) {
#pragma clang fp contract(off)
    float Bv = 2.0f * m;
    float t  = A - Bv;
    return t + Ck;
}
__device__ __forceinline__ unsigned short bf16_rne(float x) {
    unsigned u = __float_as_uint(x);
    unsigned r = u + 0x7fff + ((u >> 16) & 1);
    return (unsigned short)(r >> 16);
}
__device__ __forceinline__ float bf16_tof(unsigned short h) {
    return __uint_as_float(((unsigned)h) << 16);
}

// ---------------- K1: fused prep — e-norms (coalesced) + w-norms + wfrag ----------------
#define PRS 260
__global__ __launch_bounds__(256) void k_prep(
        const float* __restrict__ eg, const float* __restrict__ wg,
        float* __restrict__ rn, float* __restrict__ wn,
        unsigned short* __restrict__ wfrag) {
    __shared__ __align__(16) float es[32 * PRS];
    const int tid = threadIdx.x;
    const int bx  = blockIdx.x;
    if (bx < 2048) {
        // ---- e-norms: 32 rows, LDS-staged coalesced ----
        const int rowBase = bx * 32;
        #pragma unroll
        for (int j = 0; j < 8; ++j) {
            int f4 = j * 256 + tid;
            int row = f4 >> 6, k4 = f4 & 63;
            float4 v = *(const float4*)(eg + (size_t)(rowBase + row) * D_DIM + k4 * 4);
            *(float4*)&es[row * PRS + k4 * 4] = v;
        }
        __syncthreads();
        if (tid < 64) {
            int row = tid >> 1, half = tid & 1;
            float s = pw128_sq((const float4*)&es[row * PRS + half * 128]);
            float so = __shfl_xor(s, 1, 64);
            if (half == 0) rn[rowBase + row] = s + so;
        }
    } else if (bx < 2052) {
        // ---- w-norms: thread-per-row (1024 rows total) ----
        int row = (bx - 2048) * 256 + tid;
        wn[row] = rownorm_np(wg + (size_t)row * D_DIM);
    } else {
        // ---- wfrag: bf16-hi fragments only, layout [kc][col][8] ----
        int t = (bx - 2052) * 256 + tid;     // 0..32767
        int col = t >> 5, kc = t & 31;
        const float4* src = (const float4*)(wg + (size_t)col * D_DIM + kc * 8);
        float4 v0 = src[0], v1 = src[1];
        const float a[8] = {v0.x, v0.y, v0.z, v0.w, v1.x, v1.y, v1.z, v1.w};
        short8 h;
        #pragma unroll
        for (int i = 0; i < 8; ++i) h[i] = (short)bf16_rne(a[i]);
        *(short8*)(wfrag + ((size_t)kc * 1024 + col) * 8) = h;
    }
}

// ---------------- K2: MFMA split-2 distance — A in registers, full col sweep ----------------
// grid(512): block = 128 rows; wave = 32 rows (2 mt); 16 col-phases of 64 codes
// terms: ah*bh + al*bh  (W-lo dropped; TAU widened to cover)
__global__ __launch_bounds__(256, 2) void k_dist(
        const float* __restrict__ eg, const unsigned short* __restrict__ wfrag,
        const float* __restrict__ rn, const float* __restrict__ wn,
        int* __restrict__ idx_ws, int* __restrict__ fixlist, int* __restrict__ fixcnt) {
    __shared__ __align__(16) unsigned short Bs[32 * BLINE];
    const int tid  = threadIdx.x;
    const int lane = tid & 63;
    const int wv   = tid >> 6;
    const int q    = lane >> 4;
    const int m15  = lane & 15;
    const int waveRow = blockIdx.x * 128 + wv * 32;

    // ---- A fragments: load fp32, split hi/lo, keep in registers for whole kernel ----
    short8 afh[2][8], afl[2][8];
    #pragma unroll
    for (int mt = 0; mt < 2; ++mt) {
        const float* rowp = eg + (size_t)(waveRow + mt * 16 + m15) * D_DIM + q * 8;
        #pragma unroll
        for (int win = 0; win < 8; ++win) {
            const float4* pa = (const float4*)(rowp + win * 32);
            float4 x0 = pa[0], x1 = pa[1];
            const float a[8] = {x0.x, x0.y, x0.z, x0.w, x1.x, x1.y, x1.z, x1.w};
            short8 h, l;
            #pragma unroll
            for (int i = 0; i < 8; ++i) {
                unsigned short hh = bf16_rne(a[i]);
                h[i] = (short)hh;
                l[i] = (short)bf16_rne(a[i] - bf16_tof(hh));
            }
            afh[mt][win] = h;
            afl[mt][win] = l;
        }
    }
    // row norms for this lane's 8 C-row slots (row = mt*16 + q*4 + reg)
    float rnv[8];
    #pragma unroll
    for (int mt = 0; mt < 2; ++mt)
        #pragma unroll
        for (int reg = 0; reg < 4; ++reg)
            rnv[mt * 4 + reg] = rn[waveRow + mt * 16 + q * 4 + reg];

    float best[8], sec[8];
    int bidx[8];
    #pragma unroll
    for (int s = 0; s < 8; ++s) { best[s] = 3.4e38f; sec[s] = 3.4e38f; bidx[s] = 0; }

    for (int cb = 0; cb < 16; ++cb) {
        __syncthreads();   // Bs reuse guard
        // stage this phase's B tile: 32 lines of 1 KB via global_load_lds, 8 lines/wave
        #pragma unroll
        for (int t = 0; t < 8; ++t) {
            int L = wv * 8 + t;   // = kc 0..31
            const unsigned short* src = wfrag + ((size_t)L * 1024 + cb * 64) * 8 + lane * 8;
            __builtin_amdgcn_global_load_lds(
                (const __attribute__((address_space(1))) unsigned int*)src,
                (__attribute__((address_space(3))) unsigned int*)&Bs[L * BLINE],
                16, 0, 0);
        }
        __syncthreads();   // compiler emits vmcnt(0) drain before barrier

        floatx4 acc[2][4];
        #pragma unroll
        for (int mt = 0; mt < 2; ++mt)
            #pragma unroll
            for (int nt = 0; nt < 4; ++nt)
                acc[mt][nt] = (floatx4){0.f, 0.f, 0.f, 0.f};

        #pragma unroll
        for (int nt = 0; nt < 4; ++nt) {
            #pragma unroll
            for (int win = 0; win < 8; ++win) {
                int kc = win * 4 + q;
                short8 bfh = *(short8*)&Bs[kc * BLINE + (nt * 16 + m15) * 8];
                acc[0][nt] = __builtin_amdgcn_mfma_f32_16x16x32_bf16(afh[0][win], bfh, acc[0][nt], 0, 0, 0);
                acc[0][nt] = __builtin_amdgcn_mfma_f32_16x16x32_bf16(afl[0][win], bfh, acc[0][nt], 0, 0, 0);
                acc[1][nt] = __builtin_amdgcn_mfma_f32_16x16x32_bf16(afh[1][win], bfh, acc[1][nt], 0, 0, 0);
                acc[1][nt] = __builtin_amdgcn_mfma_f32_16x16x32_bf16(afl[1][win], bfh, acc[1][nt], 0, 0, 0);
            }
        }
        // fold distances into running top-2 (cols ascend with cb,nt -> first-min kept)
        #pragma unroll
        for (int nt = 0; nt < 4; ++nt) {
            int col = cb * 64 + nt * 16 + m15;
            float Ck = wn[col];
            #pragma unroll
            for (int mt = 0; mt < 2; ++mt)
                #pragma unroll
                for (int reg = 0; reg < 4; ++reg) {
                    int s = mt * 4 + reg;
                    float d = np_dist(rnv[s], acc[mt][nt][reg], Ck);
                    if (d < best[s])     { sec[s] = best[s]; best[s] = d; bidx[s] = col; }
                    else if (d < sec[s]) { sec[s] = d; }
                }
        }
    }

    // butterfly top-2 merge across the 16 m15 lanes (rows live per (q,mt,reg))
    #pragma unroll
    for (int s = 0; s < 8; ++s) {
        float b = best[s], se = sec[s];
        int ix = bidx[s];
        #pragma unroll
        for (int m = 1; m < 16; m <<= 1) {
            float bo = __shfl_xor(b, m, 64);
            float so = __shfl_xor(se, m, 64);
            int   io = __shfl_xor(ix, m, 64);
            float ns = fminf(fminf(se, so), fmaxf(b, bo));
            if (bo < b || (bo == b && io < ix)) { b = bo; ix = io; }
            se = ns;
        }
        if (m15 == 0) {
            int row = waveRow + (s >> 2) * 16 + q * 4 + (s & 3);
            idx_ws[row] = ix;
            if (se - b < TAU) {
                int p = atomicAdd(fixcnt, 1);
                fixlist[p] = row;
            }
        }
    }
}

// ---------------- K3: fp64 np-exact recheck — 8 rows/group, 4 blocks/group ----------------
// Each tile = (group, chunk): 8 flagged rows x 256 codes, one code per thread.
// Wave-butterfly min on u64 (distkey<<32 | idx), one atomicMin per wave per row.
#define FG_ROWS 8
__global__ __launch_bounds__(256) void k_fixup(
        const float* __restrict__ eg, const float* __restrict__ wg,
        const float* __restrict__ rn, const float* __restrict__ wnorm,
        const int* __restrict__ fixlist, const int* __restrict__ fixcnt,
        unsigned long long* __restrict__ keys) {
    __shared__ double xs[FG_ROWS][D_DIM];
    const int tid = threadIdx.x;
    const int cnt = *fixcnt;
    if (cnt == 0) return;
    const int ngroups = (cnt + FG_ROWS - 1) / FG_ROWS;
    const int ntiles  = ngroups * 4;
    for (int t = blockIdx.x; t < ntiles; t += gridDim.x) {
        const int g     = t >> 2;
        const int chunk = t & 3;
        __syncthreads();   // xs reuse guard across grid-stride tiles
        int rows[FG_ROWS];
        #pragma unroll
        for (int i = 0; i < FG_ROWS; ++i) {
            int j = g * FG_ROWS + i;
            rows[i] = fixlist[j < cnt ? j : cnt - 1];
        }
        #pragma unroll
        for (int i = 0; i < FG_ROWS; ++i)
            xs[i][tid] = (double)eg[(size_t)rows[i] * D_DIM + tid];
        __syncthreads();
        float An[FG_ROWS];
        #pragma unroll
        for (int i = 0; i < FG_ROWS; ++i) An[i] = rn[rows[i]];

        const int k = chunk * 256 + tid;
        const float4* wr = (const float4*)(wg + (size_t)k * D_DIM);
        double s[FG_ROWS];
        #pragma unroll
        for (int i = 0; i < FG_ROWS; ++i) s[i] = 0.0;
        for (int i = 0; i < D_DIM / 4; ++i) {
            float4 f = wr[i];
            double f0 = f.x, f1 = f.y, f2 = f.z, f3 = f.w;
            #pragma unroll
            for (int r = 0; r < FG_ROWS; ++r)
                s[r] += xs[r][4*i] * f0 + xs[r][4*i+1] * f1
                      + xs[r][4*i+2] * f2 + xs[r][4*i+3] * f3;
        }
        const float Cw = wnorm[k];
        #pragma unroll
        for (int r = 0; r < FG_ROWS; ++r) {
            float d = np_dist(An[r], (float)s[r], Cw);
            unsigned u = __float_as_uint(d);
            unsigned key32 = u ^ (((unsigned)((int)u >> 31)) | 0x80000000u);
            unsigned long long key = ((unsigned long long)key32 << 32) | (unsigned)k;
            #pragma unroll
            for (int m = 1; m < 64; m <<= 1) {
                unsigned long long o = __shfl_xor(key, m, 64);
                key = (o < key) ? o : key;
            }
            int j = g * FG_ROWS + r;
            if ((tid & 63) == 0 && j < cnt) atomicMin(&keys[j], key);
        }
    }
}

// ---------------- K3b: scatter fixup winners back into idx_ws ----------------
__global__ void k_fixscatter(const int* __restrict__ fixlist, const int* __restrict__ fixcnt,
                             const unsigned long long* __restrict__ keys,
                             int* __restrict__ idx_ws) {
    const int cnt = *fixcnt;
    for (int j = blockIdx.x * blockDim.x + threadIdx.x; j < cnt;
         j += gridDim.x * blockDim.x)
        idx_ws[fixlist[j]] = (int)(keys[j] & 0xFFFFFFFFull);
}

// ---------------- K4: gather + STE + loss partials + histogram (float4 vectorized) ----------------
__global__ void k_final(const float* __restrict__ eg, const float* __restrict__ wg,
                        const int* __restrict__ idx_ws, float* __restrict__ qout,
                        float* __restrict__ iout, int* __restrict__ hist,
                        double* __restrict__ partials) {
    const int tid  = threadIdx.x;
    const int sub  = tid >> 6;      // 0..3: row within quad
    const int lane = tid & 63;      // float4 column
    const int rowBase = blockIdx.x * 16;
    double acc = 0.0;
    #pragma unroll
    for (int g = 0; g < 4; ++g) {
        int row = rowBase + g * 4 + sub;
        int k = idx_ws[row];
        float4 ev = ((const float4*)(eg + (size_t)row * D_DIM))[lane];
        float4 wv = ((const float4*)(wg + (size_t)k   * D_DIM))[lane];
        float dx = wv.x - ev.x, dy = wv.y - ev.y, dz = wv.z - ev.z, dw = wv.w - ev.w;
        float4 qv = {ev.x + dx, ev.y + dy, ev.z + dz, ev.w + dw};
        ((float4*)(qout + (size_t)row * D_DIM))[lane] = qv;
        acc += (double)(dx * dx) + (double)(dy * dy)
             + (double)(dz * dz) + (double)(dw * dw);
        if (lane == 0) {
            iout[row] = (float)k;
            atomicAdd(&hist[k], 1);
        }
    }
    __shared__ double red[256];
    red[tid] = acc;
    __syncthreads();
    for (int st = 128; st > 0; st >>= 1) {
        if (tid < st) red[tid] += red[tid + st];
        __syncthreads();
    }
    if (tid == 0) partials[blockIdx.x] = red[0];
}

// ---------------- K5: scalars ----------------
__global__ void k_scalars(const int* __restrict__ hist, const double* __restrict__ partials,
                          float* __restrict__ sout) {
    const int tid = threadIdx.x;
    double s = 0.0;
    for (int j = tid; j < N_ROWS / 16; j += 256) s += partials[j];
    int m = 0;
    for (int j = tid; j < K_CB; j += 256) m = max(m, hist[j]);
    __shared__ double rs[256];
    __shared__ int    rm[256];
    rs[tid] = s; rm[tid] = m;
    __syncthreads();
    for (int st = 128; st > 0; st >>= 1) {
        if (tid < st) { rs[tid] += rs[tid + st]; rm[tid] = max(rm[tid], rm[tid + st]); }
        __syncthreads();
    }
    if (tid == 0) {
        sout[0] = (float)(rs[0] / (double)((size_t)N_ROWS * D_DIM));
        sout[1] = (float)rm[0] / 65536.0f;
    }
}

extern "C" void kernel_launch(void* const* d_in, const int* in_sizes, int n_in,
                              void* d_out, int out_size, void* d_ws, size_t ws_size,
                              hipStream_t stream) {
    const float* e = (const float*)d_in[0];
    const float* w = (const float*)d_in[1];
    float* out  = (float*)d_out;
    float* qout = out;
    float* iout = out + (size_t)N_ROWS * D_DIM;
    float* sout = iout + N_ROWS;

    char* ws = (char*)d_ws;
    float*  rn       = (float*) (ws + OFF_RN);
    float*  wn       = (float*) (ws + OFF_WN);
    int*    fixcnt   = (int*)   (ws + OFF_FIXCNT);
    int*    hist     = (int*)   (ws + OFF_HIST);
    int*    idxp     = (int*)   (ws + OFF_IDX);
    int*    list     = (int*)   (ws + OFF_LIST);
    double* partials = (double*)(ws + OFF_PART);
    unsigned short* wfrag = (unsigned short*)(ws + OFF_WFRAG);
    unsigned long long* keys = (unsigned long long*)(ws + OFF_KEYS);

    hipMemsetAsync(ws + OFF_FIXCNT, 0, 4352, stream);        // fixcnt + hist
    hipMemsetAsync(ws + OFF_KEYS, 0xFF, 524288, stream);     // keys = u64 max

    hipLaunchKernelGGL(k_prep,       dim3(2180),        dim3(256), 0, stream, e, w, rn, wn, wfrag);
    hipLaunchKernelGGL(k_dist,       dim3(512),         dim3(256), 0, stream, e, wfrag, rn, wn, idxp, list, fixcnt);
    hipLaunchKernelGGL(k_fixup,      dim3(2048),        dim3(256), 0, stream, e, w, rn, wn, list, fixcnt, keys);
    hipLaunchKernelGGL(k_fixscatter, dim3(64),          dim3(256), 0, stream, list, fixcnt, keys, idxp);
    hipLaunchKernelGGL(k_final,      dim3(N_ROWS / 16), dim3(256), 0, stream, e, w, idxp, qout, iout, hist, partials);
    hipLaunchKernelGGL(k_scalars,    dim3(1),           dim3(256), 0, stream, hist, partials, sout);
}

// Round 3
// 363.690 us; speedup vs baseline: 1.1019x; 1.0268x over previous
//
#include <hip/hip_runtime.h>

typedef __attribute__((ext_vector_type(8))) short short8;
typedef __attribute__((ext_vector_type(4))) float floatx4;

#define N_ROWS 65536
#define K_CB   1024
#define D_DIM  256

// 2-term split (ah*bh + al*bh): W's bf16 residual is dropped; its error
// (sigma ~2-3e-5 on distances) plus fma-reordering noise is folded into the
// recheck band.
#define TAU 3.0e-4f
#define BLINE 520   // shorts per B LDS line (512 data + 8 pad = 1040 B; staggers banks by 4/line)

// ws layout (bytes) — ~1.9 MB, ws_size >= 14 MB proven on this harness
#define OFF_RN     0         // float[65536]
#define OFF_WN     262144    // float[1024]
#define OFF_FIXCNT 266240    // int
#define OFF_HIST   266496    // int[1024]
#define OFF_IDX    270592    // int[65536]
#define OFF_LIST   532736    // int[65536]
#define OFF_PART   794880    // double[4096]
#define OFF_WFRAG  827392    // ushort[32*1024*8] = 512 KB (hi fragments only)
#define OFF_KEYS   1351680   // u64[65536] = 512 KB (fixup argmin keys)

// ---- numpy pairwise fp32 sum-of-squares emulation (contract off!) ----
__device__ __forceinline__ float pw128_sq(const float4* p) {
#pragma clang fp contract(off)
    float4 q0 = p[0], q1 = p[1];
    float r0 = q0.x * q0.x, r1 = q0.y * q0.y, r2 = q0.z * q0.z, r3 = q0.w * q0.w;
    float r4 = q1.x * q1.x, r5 = q1.y * q1.y, r6 = q1.z * q1.z, r7 = q1.w * q1.w;
    for (int i = 1; i < 16; ++i) {
        float4 u0 = p[2 * i], u1 = p[2 * i + 1];
        r0 = r0 + u0.x * u0.x; r1 = r1 + u0.y * u0.y;
        r2 = r2 + u0.z * u0.z; r3 = r3 + u0.w * u0.w;
        r4 = r4 + u1.x * u1.x; r5 = r5 + u1.y * u1.y;
        r6 = r6 + u1.z * u1.z; r7 = r7 + u1.w * u1.w;
    }
    return ((r0 + r1) + (r2 + r3)) + ((r4 + r5) + (r6 + r7));
}
__device__ __forceinline__ float rownorm_np(const float* row) {
#pragma clang fp contract(off)
    float s0 = pw128_sq((const float4*)row);
    float s1 = pw128_sq((const float4*)(row + 128));
    return s0 + s1;
}
__device__ __forceinline__ float np_dist(float A, float m, float Ck) {
#pragma clang fp contract(off)
    float Bv = 2.0f * m;
    float t  = A - Bv;
    return t + Ck;
}
__device__ __forceinline__ unsigned short bf16_rne(float x) {
    unsigned u = __float_as_uint(x);
    unsigned r = u + 0x7fff + ((u >> 16) & 1);
    return (unsigned short)(r >> 16);
}
__device__ __forceinline__ float bf16_tof(unsigned short h) {
    return __uint_as_float(((unsigned)h) << 16);
}

// ---------------- K1: fused prep — e-norms (coalesced) + w-norms + wfrag ----------------
#define PRS 260
__global__ __launch_bounds__(256) void k_prep(
        const float* __restrict__ eg, const float* __restrict__ wg,
        float* __restrict__ rn, float* __restrict__ wn,
        unsigned short* __restrict__ wfrag) {
    __shared__ __align__(16) float es[32 * PRS];
    const int tid = threadIdx.x;
    const int bx  = blockIdx.x;
    if (bx < 2048) {
        // ---- e-norms: 32 rows, LDS-staged coalesced ----
        const int rowBase = bx * 32;
        #pragma unroll
        for (int j = 0; j < 8; ++j) {
            int f4 = j * 256 + tid;
            int row = f4 >> 6, k4 = f4 & 63;
            float4 v = *(const float4*)(eg + (size_t)(rowBase + row) * D_DIM + k4 * 4);
            *(float4*)&es[row * PRS + k4 * 4] = v;
        }
        __syncthreads();
        if (tid < 64) {
            int row = tid >> 1, half = tid & 1;
            float s = pw128_sq((const float4*)&es[row * PRS + half * 128]);
            float so = __shfl_xor(s, 1, 64);
            if (half == 0) rn[rowBase + row] = s + so;
        }
    } else if (bx < 2052) {
        // ---- w-norms: thread-per-row (1024 rows total) ----
        int row = (bx - 2048) * 256 + tid;
        wn[row] = rownorm_np(wg + (size_t)row * D_DIM);
    } else {
        // ---- wfrag: bf16-hi fragments only, layout [kc][col][8] ----
        int t = (bx - 2052) * 256 + tid;     // 0..32767
        int col = t >> 5, kc = t & 31;
        const float4* src = (const float4*)(wg + (size_t)col * D_DIM + kc * 8);
        float4 v0 = src[0], v1 = src[1];
        const float a[8] = {v0.x, v0.y, v0.z, v0.w, v1.x, v1.y, v1.z, v1.w};
        short8 h;
        #pragma unroll
        for (int i = 0; i < 8; ++i) h[i] = (short)bf16_rne(a[i]);
        *(short8*)(wfrag + ((size_t)kc * 1024 + col) * 8) = h;
    }
}

// ---------------- K2: MFMA split-2 distance — 16 rows/wave, full col sweep ----------------
// grid(1024): block = 64 rows; wave = 16 rows; 16 col-phases of 64 codes
// distance d' = fma(-2, m, Ck): the per-row ||e||^2 constant cancels in argmin
// and in the (sec-best) band; reordering noise vs numpy covered by TAU/fixup.
__global__ __launch_bounds__(256, 4) void k_dist(
        const float* __restrict__ eg, const unsigned short* __restrict__ wfrag,
        const float* __restrict__ wn,
        int* __restrict__ idx_ws, int* __restrict__ fixlist, int* __restrict__ fixcnt) {
    __shared__ __align__(16) unsigned short Bs[32 * BLINE];
    __shared__ float wnS[K_CB];
    const int tid  = threadIdx.x;
    const int lane = tid & 63;
    const int wv   = tid >> 6;
    const int q    = lane >> 4;
    const int m15  = lane & 15;
    const int waveRow = blockIdx.x * 64 + wv * 16;

    // ---- wn -> LDS once (covered by first top-of-loop barrier) ----
    #pragma unroll
    for (int i = 0; i < 4; ++i) wnS[tid + i * 256] = wn[tid + i * 256];

    // ---- A fragments: load fp32, split hi/lo, keep in registers for whole kernel ----
    short8 afh[8], afl[8];
    {
        const float* rowp = eg + (size_t)(waveRow + m15) * D_DIM + q * 8;
        #pragma unroll
        for (int win = 0; win < 8; ++win) {
            const float4* pa = (const float4*)(rowp + win * 32);
            float4 x0 = pa[0], x1 = pa[1];
            const float a[8] = {x0.x, x0.y, x0.z, x0.w, x1.x, x1.y, x1.z, x1.w};
            short8 h, l;
            #pragma unroll
            for (int i = 0; i < 8; ++i) {
                unsigned short hh = bf16_rne(a[i]);
                h[i] = (short)hh;
                l[i] = (short)bf16_rne(a[i] - bf16_tof(hh));
            }
            afh[win] = h;
            afl[win] = l;
        }
    }

    float best[4], sec[4];
    int bidx[4];
    #pragma unroll
    for (int s = 0; s < 4; ++s) { best[s] = 3.4e38f; sec[s] = 3.4e38f; bidx[s] = 0; }

    for (int cb = 0; cb < 16; ++cb) {
        __syncthreads();   // Bs reuse guard (also publishes wnS on first pass)
        // stage this phase's B tile: 32 lines of 1 KB via global_load_lds, 8 lines/wave
        #pragma unroll
        for (int t = 0; t < 8; ++t) {
            int L = wv * 8 + t;   // = kc 0..31
            const unsigned short* src = wfrag + ((size_t)L * 1024 + cb * 64) * 8 + lane * 8;
            __builtin_amdgcn_global_load_lds(
                (const __attribute__((address_space(1))) unsigned int*)src,
                (__attribute__((address_space(3))) unsigned int*)&Bs[L * BLINE],
                16, 0, 0);
        }
        __syncthreads();   // compiler emits vmcnt(0) drain before barrier

        floatx4 acc[4];
        #pragma unroll
        for (int nt = 0; nt < 4; ++nt)
            acc[nt] = (floatx4){0.f, 0.f, 0.f, 0.f};

        #pragma unroll
        for (int nt = 0; nt < 4; ++nt) {
            #pragma unroll
            for (int win = 0; win < 8; ++win) {
                int kc = win * 4 + q;
                short8 bfh = *(short8*)&Bs[kc * BLINE + (nt * 16 + m15) * 8];
                acc[nt] = __builtin_amdgcn_mfma_f32_16x16x32_bf16(afh[win], bfh, acc[nt], 0, 0, 0);
                acc[nt] = __builtin_amdgcn_mfma_f32_16x16x32_bf16(afl[win], bfh, acc[nt], 0, 0, 0);
            }
        }
        // fold into running top-2 (cols ascend with cb,nt -> first-min kept)
        #pragma unroll
        for (int nt = 0; nt < 4; ++nt) {
            int col = cb * 64 + nt * 16 + m15;
            float Ck = wnS[col];
            #pragma unroll
            for (int reg = 0; reg < 4; ++reg) {
                float d = __builtin_fmaf(-2.0f, acc[nt][reg], Ck);
                bool lt = d < best[reg];
                sec[reg]  = __builtin_amdgcn_fmed3f(d, best[reg], sec[reg]);
                best[reg] = fminf(d, best[reg]);
                bidx[reg] = lt ? col : bidx[reg];
            }
        }
    }

    // butterfly top-2 merge across the 16 m15 lanes (rows live per (q,reg))
    #pragma unroll
    for (int s = 0; s < 4; ++s) {
        float b = best[s], se = sec[s];
        int ix = bidx[s];
        #pragma unroll
        for (int m = 1; m < 16; m <<= 1) {
            float bo = __shfl_xor(b, m, 64);
            float so = __shfl_xor(se, m, 64);
            int   io = __shfl_xor(ix, m, 64);
            float ns = fminf(fminf(se, so), fmaxf(b, bo));
            if (bo < b || (bo == b && io < ix)) { b = bo; ix = io; }
            se = ns;
        }
        if (m15 == 0) {
            int row = waveRow + q * 4 + s;
            idx_ws[row] = ix;
            if (se - b < TAU) {
                int p = atomicAdd(fixcnt, 1);
                fixlist[p] = row;
            }
        }
    }
}

// ---------------- K3: fp64 np-exact recheck — 8 rows/group, 4 blocks/group ----------------
// Each tile = (group, chunk): 8 flagged rows x 256 codes, one code per thread.
// Wave-butterfly min on u64 (distkey<<32 | idx), one atomicMin per wave per row.
#define FG_ROWS 8
__global__ __launch_bounds__(256) void k_fixup(
        const float* __restrict__ eg, const float* __restrict__ wg,
        const float* __restrict__ rn, const float* __restrict__ wnorm,
        const int* __restrict__ fixlist, const int* __restrict__ fixcnt,
        unsigned long long* __restrict__ keys) {
    __shared__ double xs[FG_ROWS][D_DIM];
    const int tid = threadIdx.x;
    const int cnt = *fixcnt;
    if (cnt == 0) return;
    const int ngroups = (cnt + FG_ROWS - 1) / FG_ROWS;
    const int ntiles  = ngroups * 4;
    for (int t = blockIdx.x; t < ntiles; t += gridDim.x) {
        const int g     = t >> 2;
        const int chunk = t & 3;
        __syncthreads();   // xs reuse guard across grid-stride tiles
        int rows[FG_ROWS];
        #pragma unroll
        for (int i = 0; i < FG_ROWS; ++i) {
            int j = g * FG_ROWS + i;
            rows[i] = fixlist[j < cnt ? j : cnt - 1];
        }
        #pragma unroll
        for (int i = 0; i < FG_ROWS; ++i)
            xs[i][tid] = (double)eg[(size_t)rows[i] * D_DIM + tid];
        __syncthreads();
        float An[FG_ROWS];
        #pragma unroll
        for (int i = 0; i < FG_ROWS; ++i) An[i] = rn[rows[i]];

        const int k = chunk * 256 + tid;
        const float4* wr = (const float4*)(wg + (size_t)k * D_DIM);
        double s[FG_ROWS];
        #pragma unroll
        for (int i = 0; i < FG_ROWS; ++i) s[i] = 0.0;
        for (int i = 0; i < D_DIM / 4; ++i) {
            float4 f = wr[i];
            double f0 = f.x, f1 = f.y, f2 = f.z, f3 = f.w;
            #pragma unroll
            for (int r = 0; r < FG_ROWS; ++r)
                s[r] += xs[r][4*i] * f0 + xs[r][4*i+1] * f1
                      + xs[r][4*i+2] * f2 + xs[r][4*i+3] * f3;
        }
        const float Cw = wnorm[k];
        #pragma unroll
        for (int r = 0; r < FG_ROWS; ++r) {
            float d = np_dist(An[r], (float)s[r], Cw);
            unsigned u = __float_as_uint(d);
            unsigned key32 = u ^ (((unsigned)((int)u >> 31)) | 0x80000000u);
            unsigned long long key = ((unsigned long long)key32 << 32) | (unsigned)k;
            #pragma unroll
            for (int m = 1; m < 64; m <<= 1) {
                unsigned long long o = __shfl_xor(key, m, 64);
                key = (o < key) ? o : key;
            }
            int j = g * FG_ROWS + r;
            if ((tid & 63) == 0 && j < cnt) atomicMin(&keys[j], key);
        }
    }
}

// ---------------- K3b: scatter fixup winners back into idx_ws ----------------
__global__ void k_fixscatter(const int* __restrict__ fixlist, const int* __restrict__ fixcnt,
                             const unsigned long long* __restrict__ keys,
                             int* __restrict__ idx_ws) {
    const int cnt = *fixcnt;
    for (int j = blockIdx.x * blockDim.x + threadIdx.x; j < cnt;
         j += gridDim.x * blockDim.x)
        idx_ws[fixlist[j]] = (int)(keys[j] & 0xFFFFFFFFull);
}

// ---------------- K4: gather + STE + loss partials + histogram (float4 vectorized) ----------------
__global__ void k_final(const float* __restrict__ eg, const float* __restrict__ wg,
                        const int* __restrict__ idx_ws, float* __restrict__ qout,
                        float* __restrict__ iout, int* __restrict__ hist,
                        double* __restrict__ partials) {
    const int tid  = threadIdx.x;
    const int sub  = tid >> 6;      // 0..3: row within quad
    const int lane = tid & 63;      // float4 column
    const int rowBase = blockIdx.x * 16;
    double acc = 0.0;
    #pragma unroll
    for (int g = 0; g < 4; ++g) {
        int row = rowBase + g * 4 + sub;
        int k = idx_ws[row];
        float4 ev = ((const float4*)(eg + (size_t)row * D_DIM))[lane];
        float4 wv = ((const float4*)(wg + (size_t)k   * D_DIM))[lane];
        float dx = wv.x - ev.x, dy = wv.y - ev.y, dz = wv.z - ev.z, dw = wv.w - ev.w;
        float4 qv = {ev.x + dx, ev.y + dy, ev.z + dz, ev.w + dw};
        ((float4*)(qout + (size_t)row * D_DIM))[lane] = qv;
        acc += (double)(dx * dx) + (double)(dy * dy)
             + (double)(dz * dz) + (double)(dw * dw);
        if (lane == 0) {
            iout[row] = (float)k;
            atomicAdd(&hist[k], 1);
        }
    }
    __shared__ double red[256];
    red[tid] = acc;
    __syncthreads();
    for (int st = 128; st > 0; st >>= 1) {
        if (tid < st) red[tid] += red[tid + st];
        __syncthreads();
    }
    if (tid == 0) partials[blockIdx.x] = red[0];
}

// ---------------- K5: scalars ----------------
__global__ void k_scalars(const int* __restrict__ hist, const double* __restrict__ partials,
                          float* __restrict__ sout) {
    const int tid = threadIdx.x;
    double s = 0.0;
    for (int j = tid; j < N_ROWS / 16; j += 256) s += partials[j];
    int m = 0;
    for (int j = tid; j < K_CB; j += 256) m = max(m, hist[j]);
    __shared__ double rs[256];
    __shared__ int    rm[256];
    rs[tid] = s; rm[tid] = m;
    __syncthreads();
    for (int st = 128; st > 0; st >>= 1) {
        if (tid < st) { rs[tid] += rs[tid + st]; rm[tid] = max(rm[tid], rm[tid + st]); }
        __syncthreads();
    }
    if (tid == 0) {
        sout[0] = (float)(rs[0] / (double)((size_t)N_ROWS * D_DIM));
        sout[1] = (float)rm[0] / 65536.0f;
    }
}

extern "C" void kernel_launch(void* const* d_in, const int* in_sizes, int n_in,
                              void* d_out, int out_size, void* d_ws, size_t ws_size,
                              hipStream_t stream) {
    const float* e = (const float*)d_in[0];
    const float* w = (const float*)d_in[1];
    float* out  = (float*)d_out;
    float* qout = out;
    float* iout = out + (size_t)N_ROWS * D_DIM;
    float* sout = iout + N_ROWS;

    char* ws = (char*)d_ws;
    float*  rn       = (float*) (ws + OFF_RN);
    float*  wn       = (float*) (ws + OFF_WN);
    int*    fixcnt   = (int*)   (ws + OFF_FIXCNT);
    int*    hist     = (int*)   (ws + OFF_HIST);
    int*    idxp     = (int*)   (ws + OFF_IDX);
    int*    list     = (int*)   (ws + OFF_LIST);
    double* partials = (double*)(ws + OFF_PART);
    unsigned short* wfrag = (unsigned short*)(ws + OFF_WFRAG);
    unsigned long long* keys = (unsigned long long*)(ws + OFF_KEYS);

    hipMemsetAsync(ws + OFF_FIXCNT, 0, 4352, stream);        // fixcnt + hist
    hipMemsetAsync(ws + OFF_KEYS, 0xFF, 524288, stream);     // keys = u64 max

    hipLaunchKernelGGL(k_prep,       dim3(2180),        dim3(256), 0, stream, e, w, rn, wn, wfrag);
    hipLaunchKernelGGL(k_dist,       dim3(1024),        dim3(256), 0, stream, e, wfrag, wn, idxp, list, fixcnt);
    hipLaunchKernelGGL(k_fixup,      dim3(2048),        dim3(256), 0, stream, e, w, rn, wn, list, fixcnt, keys);
    hipLaunchKernelGGL(k_fixscatter, dim3(64),          dim3(256), 0, stream, list, fixcnt, keys, idxp);
    hipLaunchKernelGGL(k_final,      dim3(N_ROWS / 16), dim3(256), 0, stream, e, w, idxp, qout, iout, hist, partials);
    hipLaunchKernelGGL(k_scalars,    dim3(1),           dim3(256), 0, stream, hist, partials, sout);
}

// Round 4
// 347.116 us; speedup vs baseline: 1.1545x; 1.0477x over previous
//
#include <hip/hip_runtime.h>

typedef __attribute__((ext_vector_type(8))) short short8;
typedef __attribute__((ext_vector_type(4))) float floatx4;

#define N_ROWS 65536
#define K_CB   1024
#define D_DIM  256

// 2-term split (ah*bh + al*bh): W's bf16 residual is dropped; its error
// (sigma ~2-3e-5 on distances) plus fma-reordering noise is folded into the
// recheck band.
#define TAU 3.0e-4f
#define BLINE 520   // shorts per B LDS line (512 data + 8 pad = 1040 B; staggers banks by 4/line)

// ws layout (bytes) — ~2.9 MB, ws_size >= 14 MB proven on this harness
#define OFF_RN     0         // float[65536]
#define OFF_WN     262144    // float[1024]
#define OFF_FIXCNT 266240    // int
#define OFF_HIST   266496    // int[1024]
#define OFF_IDX    270592    // int[65536]
#define OFF_LIST   532736    // int[65536]
#define OFF_PART   794880    // double[4096]
#define OFF_WFRAG  827392    // ushort[32*1024*8] = 512 KB (hi fragments only)
#define OFF_KEYS   1351680   // u64[65536] = 512 KB (fixup argmin keys)
#define OFF_WT     1875968   // float[256*1024] = 1 MB (W transposed [d][k])

// ---- numpy pairwise fp32 sum-of-squares emulation (contract off!) ----
__device__ __forceinline__ float pw128_sq(const float4* p) {
#pragma clang fp contract(off)
    float4 q0 = p[0], q1 = p[1];
    float r0 = q0.x * q0.x, r1 = q0.y * q0.y, r2 = q0.z * q0.z, r3 = q0.w * q0.w;
    float r4 = q1.x * q1.x, r5 = q1.y * q1.y, r6 = q1.z * q1.z, r7 = q1.w * q1.w;
    for (int i = 1; i < 16; ++i) {
        float4 u0 = p[2 * i], u1 = p[2 * i + 1];
        r0 = r0 + u0.x * u0.x; r1 = r1 + u0.y * u0.y;
        r2 = r2 + u0.z * u0.z; r3 = r3 + u0.w * u0.w;
        r4 = r4 + u1.x * u1.x; r5 = r5 + u1.y * u1.y;
        r6 = r6 + u1.z * u1.z; r7 = r7 + u1.w * u1.w;
    }
    return ((r0 + r1) + (r2 + r3)) + ((r4 + r5) + (r6 + r7));
}
__device__ __forceinline__ float rownorm_np(const float* row) {
#pragma clang fp contract(off)
    float s0 = pw128_sq((const float4*)row);
    float s1 = pw128_sq((const float4*)(row + 128));
    return s0 + s1;
}
__device__ __forceinline__ float np_dist(float A, float m, float Ck) {
#pragma clang fp contract(off)
    float Bv = 2.0f * m;
    float t  = A - Bv;
    return t + Ck;
}
__device__ __forceinline__ unsigned short bf16_rne(float x) {
    unsigned u = __float_as_uint(x);
    unsigned r = u + 0x7fff + ((u >> 16) & 1);
    return (unsigned short)(r >> 16);
}
__device__ __forceinline__ float bf16_tof(unsigned short h) {
    return __uint_as_float(((unsigned)h) << 16);
}

// ---------------- K1: fused prep — e-norms + w-norms + wfrag + wT ----------------
#define PRS 260
__global__ __launch_bounds__(256) void k_prep(
        const float* __restrict__ eg, const float* __restrict__ wg,
        float* __restrict__ rn, float* __restrict__ wn,
        unsigned short* __restrict__ wfrag, float* __restrict__ wt) {
    __shared__ __align__(16) float es[32 * PRS];
    const int tid = threadIdx.x;
    const int bx  = blockIdx.x;
    if (bx < 2048) {
        // ---- e-norms: 32 rows, LDS-staged coalesced ----
        const int rowBase = bx * 32;
        #pragma unroll
        for (int j = 0; j < 8; ++j) {
            int f4 = j * 256 + tid;
            int row = f4 >> 6, k4 = f4 & 63;
            float4 v = *(const float4*)(eg + (size_t)(rowBase + row) * D_DIM + k4 * 4);
            *(float4*)&es[row * PRS + k4 * 4] = v;
        }
        __syncthreads();
        if (tid < 64) {
            int row = tid >> 1, half = tid & 1;
            float s = pw128_sq((const float4*)&es[row * PRS + half * 128]);
            float so = __shfl_xor(s, 1, 64);
            if (half == 0) rn[rowBase + row] = s + so;
        }
    } else if (bx < 2052) {
        // ---- w-norms: thread-per-row (1024 rows total) ----
        int row = (bx - 2048) * 256 + tid;
        wn[row] = rownorm_np(wg + (size_t)row * D_DIM);
    } else if (bx < 2180) {
        // ---- wfrag: bf16-hi fragments only, layout [kc][col][8] ----
        int t = (bx - 2052) * 256 + tid;     // 0..32767
        int col = t >> 5, kc = t & 31;
        const float4* src = (const float4*)(wg + (size_t)col * D_DIM + kc * 8);
        float4 v0 = src[0], v1 = src[1];
        const float a[8] = {v0.x, v0.y, v0.z, v0.w, v1.x, v1.y, v1.z, v1.w};
        short8 h;
        #pragma unroll
        for (int i = 0; i < 8; ++i) h[i] = (short)bf16_rne(a[i]);
        *(short8*)(wfrag + ((size_t)kc * 1024 + col) * 8) = h;
    } else {
        // ---- wT: float transpose [d][k], 32 codes per block via LDS ----
        float (*tw)[PRS] = (float(*)[PRS])es;   // [32][260], fits exactly
        const int cb = bx - 2180;               // 0..31
        const int c0 = cb * 32;
        #pragma unroll
        for (int it = 0; it < 8; ++it) {
            int idx = it * 256 + tid;           // float4 index
            int code = idx >> 6, f4 = idx & 63;
            *(float4*)&tw[code][f4 * 4] =
                *(const float4*)(wg + (size_t)(c0 + code) * D_DIM + f4 * 4);
        }
        __syncthreads();
        const int j = tid & 31, dg = tid >> 5;  // dg 0..7
        #pragma unroll
        for (int dd = 0; dd < 32; ++dd) {
            int d = dd * 8 + dg;
            wt[(size_t)d * K_CB + c0 + j] = tw[j][d];
        }
    }
}

// ---------------- K2: MFMA split-2 distance — 16 rows/wave, full col sweep ----------------
// grid(1024): block = 64 rows; wave = 16 rows; 16 col-phases of 64 codes
// distance d' = fma(-2, m, Ck): the per-row ||e||^2 constant cancels in argmin
// and in the (sec-best) band; reordering noise vs numpy covered by TAU/fixup.
__global__ __launch_bounds__(256, 4) void k_dist(
        const float* __restrict__ eg, const unsigned short* __restrict__ wfrag,
        const float* __restrict__ wn,
        int* __restrict__ idx_ws, int* __restrict__ fixlist, int* __restrict__ fixcnt) {
    __shared__ __align__(16) unsigned short Bs[32 * BLINE];
    __shared__ float wnS[K_CB];
    const int tid  = threadIdx.x;
    const int lane = tid & 63;
    const int wv   = tid >> 6;
    const int q    = lane >> 4;
    const int m15  = lane & 15;
    const int waveRow = blockIdx.x * 64 + wv * 16;

    // ---- wn -> LDS once (covered by first top-of-loop barrier) ----
    #pragma unroll
    for (int i = 0; i < 4; ++i) wnS[tid + i * 256] = wn[tid + i * 256];

    // ---- A fragments: load fp32, split hi/lo, keep in registers for whole kernel ----
    short8 afh[8], afl[8];
    {
        const float* rowp = eg + (size_t)(waveRow + m15) * D_DIM + q * 8;
        #pragma unroll
        for (int win = 0; win < 8; ++win) {
            const float4* pa = (const float4*)(rowp + win * 32);
            float4 x0 = pa[0], x1 = pa[1];
            const float a[8] = {x0.x, x0.y, x0.z, x0.w, x1.x, x1.y, x1.z, x1.w};
            short8 h, l;
            #pragma unroll
            for (int i = 0; i < 8; ++i) {
                unsigned short hh = bf16_rne(a[i]);
                h[i] = (short)hh;
                l[i] = (short)bf16_rne(a[i] - bf16_tof(hh));
            }
            afh[win] = h;
            afl[win] = l;
        }
    }

    float best[4], sec[4];
    int bidx[4];
    #pragma unroll
    for (int s = 0; s < 4; ++s) { best[s] = 3.4e38f; sec[s] = 3.4e38f; bidx[s] = 0; }

    for (int cb = 0; cb < 16; ++cb) {
        __syncthreads();   // Bs reuse guard (also publishes wnS on first pass)
        // stage this phase's B tile: 32 lines of 1 KB via global_load_lds, 8 lines/wave
        #pragma unroll
        for (int t = 0; t < 8; ++t) {
            int L = wv * 8 + t;   // = kc 0..31
            const unsigned short* src = wfrag + ((size_t)L * 1024 + cb * 64) * 8 + lane * 8;
            __builtin_amdgcn_global_load_lds(
                (const __attribute__((address_space(1))) unsigned int*)src,
                (__attribute__((address_space(3))) unsigned int*)&Bs[L * BLINE],
                16, 0, 0);
        }
        __syncthreads();   // compiler emits vmcnt(0) drain before barrier

        floatx4 acc[4];
        #pragma unroll
        for (int nt = 0; nt < 4; ++nt)
            acc[nt] = (floatx4){0.f, 0.f, 0.f, 0.f};

        #pragma unroll
        for (int nt = 0; nt < 4; ++nt) {
            #pragma unroll
            for (int win = 0; win < 8; ++win) {
                int kc = win * 4 + q;
                short8 bfh = *(short8*)&Bs[kc * BLINE + (nt * 16 + m15) * 8];
                acc[nt] = __builtin_amdgcn_mfma_f32_16x16x32_bf16(afh[win], bfh, acc[nt], 0, 0, 0);
                acc[nt] = __builtin_amdgcn_mfma_f32_16x16x32_bf16(afl[win], bfh, acc[nt], 0, 0, 0);
            }
        }
        // fold into running top-2 (cols ascend with cb,nt -> first-min kept)
        #pragma unroll
        for (int nt = 0; nt < 4; ++nt) {
            int col = cb * 64 + nt * 16 + m15;
            float Ck = wnS[col];
            #pragma unroll
            for (int reg = 0; reg < 4; ++reg) {
                float d = __builtin_fmaf(-2.0f, acc[nt][reg], Ck);
                bool lt = d < best[reg];
                sec[reg]  = __builtin_amdgcn_fmed3f(d, best[reg], sec[reg]);
                best[reg] = fminf(d, best[reg]);
                bidx[reg] = lt ? col : bidx[reg];
            }
        }
    }

    // butterfly top-2 merge across the 16 m15 lanes (rows live per (q,reg))
    #pragma unroll
    for (int s = 0; s < 4; ++s) {
        float b = best[s], se = sec[s];
        int ix = bidx[s];
        #pragma unroll
        for (int m = 1; m < 16; m <<= 1) {
            float bo = __shfl_xor(b, m, 64);
            float so = __shfl_xor(se, m, 64);
            int   io = __shfl_xor(ix, m, 64);
            float ns = fminf(fminf(se, so), fmaxf(b, bo));
            if (bo < b || (bo == b && io < ix)) { b = bo; ix = io; }
            se = ns;
        }
        if (m15 == 0) {
            int row = waveRow + q * 4 + s;
            idx_ws[row] = ix;
            if (se - b < TAU) {
                int p = atomicAdd(fixcnt, 1);
                fixlist[p] = row;
            }
        }
    }
}

// ---------------- K3: fp64 np-exact recheck — register-blocked 4x4 ----------------
// tile = (group of 8 rows, chunk of 512 codes); thread = 4 rows x 4 codes.
// e rows broadcast from LDS (wave-uniform addr -> conflict-free); W read via
// wT[d][k] so lanes load consecutive float4s (coalesced, L2-resident).
#define FG_ROWS 8
__global__ __launch_bounds__(256) void k_fixup(
        const float* __restrict__ eg, const float* __restrict__ wt,
        const float* __restrict__ rn, const float* __restrict__ wnorm,
        const int* __restrict__ fixlist, const int* __restrict__ fixcnt,
        unsigned long long* __restrict__ keys) {
    __shared__ double xs[FG_ROWS][D_DIM];    // 16 KB
    const int tid = threadIdx.x;
    const int cnt = *fixcnt;
    if (cnt == 0) return;
    const int ngroups = (cnt + FG_ROWS - 1) / FG_ROWS;
    const int ntiles  = ngroups * 2;
    const int rowg = tid >> 7;               // 0,1 -> rows 4*rowg..4*rowg+3
    const int cg   = tid & 127;              // code group (4 codes each)
    for (int t = blockIdx.x; t < ntiles; t += gridDim.x) {
        const int g     = t >> 1;
        const int chunk = t & 1;
        __syncthreads();   // xs reuse guard across grid-stride tiles
        int rows[FG_ROWS];
        #pragma unroll
        for (int i = 0; i < FG_ROWS; ++i) {
            int j = g * FG_ROWS + i;
            rows[i] = fixlist[j < cnt ? j : cnt - 1];
        }
        #pragma unroll
        for (int i = 0; i < FG_ROWS; ++i)
            xs[i][tid] = (double)eg[(size_t)rows[i] * D_DIM + tid];
        __syncthreads();

        const int c0 = chunk * 512 + cg * 4;
        float An[4];
        #pragma unroll
        for (int r = 0; r < 4; ++r) An[r] = rn[rows[rowg * 4 + r]];
        float Cw[4];
        #pragma unroll
        for (int c = 0; c < 4; ++c) Cw[c] = wnorm[c0 + c];

        double s[4][4];
        #pragma unroll
        for (int r = 0; r < 4; ++r)
            #pragma unroll
            for (int c = 0; c < 4; ++c) s[r][c] = 0.0;

        #pragma unroll 2
        for (int d = 0; d < D_DIM; d += 2) {
            float4 wa = *(const float4*)(wt + (size_t)d * K_CB + c0);
            float4 wb = *(const float4*)(wt + (size_t)(d + 1) * K_CB + c0);
            double wad[4] = {(double)wa.x, (double)wa.y, (double)wa.z, (double)wa.w};
            double wbd[4] = {(double)wb.x, (double)wb.y, (double)wb.z, (double)wb.w};
            #pragma unroll
            for (int r = 0; r < 4; ++r) {
                double2 e2 = *(const double2*)&xs[rowg * 4 + r][d];
                #pragma unroll
                for (int c = 0; c < 4; ++c)
                    s[r][c] += e2.x * wad[c] + e2.y * wbd[c];
            }
        }

        #pragma unroll
        for (int r = 0; r < 4; ++r) {
            unsigned long long key = 0xFFFFFFFFFFFFFFFFull;
            #pragma unroll
            for (int c = 0; c < 4; ++c) {
                float dq = np_dist(An[r], (float)s[r][c], Cw[c]);
                unsigned u = __float_as_uint(dq);
                unsigned key32 = u ^ (((unsigned)((int)u >> 31)) | 0x80000000u);
                unsigned long long kk =
                    ((unsigned long long)key32 << 32) | (unsigned)(c0 + c);
                key = kk < key ? kk : key;
            }
            #pragma unroll
            for (int m = 1; m < 64; m <<= 1) {
                unsigned long long o = __shfl_xor(key, m, 64);
                key = (o < key) ? o : key;
            }
            int j = g * FG_ROWS + rowg * 4 + r;
            if ((tid & 63) == 0 && j < cnt) atomicMin(&keys[j], key);
        }
    }
}

// ---------------- K3b: scatter fixup winners back into idx_ws ----------------
__global__ void k_fixscatter(const int* __restrict__ fixlist, const int* __restrict__ fixcnt,
                             const unsigned long long* __restrict__ keys,
                             int* __restrict__ idx_ws) {
    const int cnt = *fixcnt;
    for (int j = blockIdx.x * blockDim.x + threadIdx.x; j < cnt;
         j += gridDim.x * blockDim.x)
        idx_ws[fixlist[j]] = (int)(keys[j] & 0xFFFFFFFFull);
}

// ---------------- K4: gather + STE + loss partials + histogram (float4 vectorized) ----------------
__global__ void k_final(const float* __restrict__ eg, const float* __restrict__ wg,
                        const int* __restrict__ idx_ws, float* __restrict__ qout,
                        float* __restrict__ iout, int* __restrict__ hist,
                        double* __restrict__ partials) {
    const int tid  = threadIdx.x;
    const int sub  = tid >> 6;      // 0..3: row within quad
    const int lane = tid & 63;      // float4 column
    const int rowBase = blockIdx.x * 16;
    double acc = 0.0;
    #pragma unroll
    for (int g = 0; g < 4; ++g) {
        int row = rowBase + g * 4 + sub;
        int k = idx_ws[row];
        float4 ev = ((const float4*)(eg + (size_t)row * D_DIM))[lane];
        float4 wv = ((const float4*)(wg + (size_t)k   * D_DIM))[lane];
        float dx = wv.x - ev.x, dy = wv.y - ev.y, dz = wv.z - ev.z, dw = wv.w - ev.w;
        float4 qv = {ev.x + dx, ev.y + dy, ev.z + dz, ev.w + dw};
        ((float4*)(qout + (size_t)row * D_DIM))[lane] = qv;
        acc += (double)(dx * dx) + (double)(dy * dy)
             + (double)(dz * dz) + (double)(dw * dw);
        if (lane == 0) {
            iout[row] = (float)k;
            atomicAdd(&hist[k], 1);
        }
    }
    __shared__ double red[256];
    red[tid] = acc;
    __syncthreads();
    for (int st = 128; st > 0; st >>= 1) {
        if (tid < st) red[tid] += red[tid + st];
        __syncthreads();
    }
    if (tid == 0) partials[blockIdx.x] = red[0];
}

// ---------------- K5: scalars ----------------
__global__ void k_scalars(const int* __restrict__ hist, const double* __restrict__ partials,
                          float* __restrict__ sout) {
    const int tid = threadIdx.x;
    double s = 0.0;
    for (int j = tid; j < N_ROWS / 16; j += 256) s += partials[j];
    int m = 0;
    for (int j = tid; j < K_CB; j += 256) m = max(m, hist[j]);
    __shared__ double rs[256];
    __shared__ int    rm[256];
    rs[tid] = s; rm[tid] = m;
    __syncthreads();
    for (int st = 128; st > 0; st >>= 1) {
        if (tid < st) { rs[tid] += rs[tid + st]; rm[tid] = max(rm[tid], rm[tid + st]); }
        __syncthreads();
    }
    if (tid == 0) {
        sout[0] = (float)(rs[0] / (double)((size_t)N_ROWS * D_DIM));
        sout[1] = (float)rm[0] / 65536.0f;
    }
}

extern "C" void kernel_launch(void* const* d_in, const int* in_sizes, int n_in,
                              void* d_out, int out_size, void* d_ws, size_t ws_size,
                              hipStream_t stream) {
    const float* e = (const float*)d_in[0];
    const float* w = (const float*)d_in[1];
    float* out  = (float*)d_out;
    float* qout = out;
    float* iout = out + (size_t)N_ROWS * D_DIM;
    float* sout = iout + N_ROWS;

    char* ws = (char*)d_ws;
    float*  rn       = (float*) (ws + OFF_RN);
    float*  wn       = (float*) (ws + OFF_WN);
    int*    fixcnt   = (int*)   (ws + OFF_FIXCNT);
    int*    hist     = (int*)   (ws + OFF_HIST);
    int*    idxp     = (int*)   (ws + OFF_IDX);
    int*    list     = (int*)   (ws + OFF_LIST);
    double* partials = (double*)(ws + OFF_PART);
    unsigned short* wfrag = (unsigned short*)(ws + OFF_WFRAG);
    unsigned long long* keys = (unsigned long long*)(ws + OFF_KEYS);
    float*  wt       = (float*) (ws + OFF_WT);

    hipMemsetAsync(ws + OFF_FIXCNT, 0, 4352, stream);        // fixcnt + hist
    hipMemsetAsync(ws + OFF_KEYS, 0xFF, 524288, stream);     // keys = u64 max

    hipLaunchKernelGGL(k_prep,       dim3(2212),        dim3(256), 0, stream, e, w, rn, wn, wfrag, wt);
    hipLaunchKernelGGL(k_dist,       dim3(1024),        dim3(256), 0, stream, e, wfrag, wn, idxp, list, fixcnt);
    hipLaunchKernelGGL(k_fixup,      dim3(2048),        dim3(256), 0, stream, e, wt, rn, wn, list, fixcnt, keys);
    hipLaunchKernelGGL(k_fixscatter, dim3(64),          dim3(256), 0, stream, list, fixcnt, keys, idxp);
    hipLaunchKernelGGL(k_final,      dim3(N_ROWS / 16), dim3(256), 0, stream, e, w, idxp, qout, iout, hist, partials);
    hipLaunchKernelGGL(k_scalars,    dim3(1),           dim3(256), 0, stream, hist, partials, sout);
}

// Round 5
// 315.085 us; speedup vs baseline: 1.2719x; 1.1017x over previous
//
#include <hip/hip_runtime.h>

typedef __attribute__((ext_vector_type(8))) short short8;
typedef __attribute__((ext_vector_type(4))) float floatx4;

#define N_ROWS 65536
#define K_CB   1024
#define D_DIM  256

// 2-term split (ah*bh + al*bh): W's bf16 residual is dropped; its error
// (sigma ~2-3e-5 on distances) plus fma-reordering noise is folded into the
// recheck band.
#define TAU 3.0e-4f
#define BLINE 520   // shorts per B LDS line (512 data + 8 pad = 1040 B; staggers banks by 4/line)

// ws layout (bytes) — ws_size >= 14 MB proven on this harness
#define OFF_WN     262144    // float[1024]
#define OFF_FIXCNT 266240    // int
#define OFF_HIST   266496    // int[1024]
#define OFF_IDX    270592    // int[65536]
#define OFF_LIST   532736    // int[65536]
#define OFF_PART   794880    // double[4096]
#define OFF_WFRAG  827392    // ushort[32*1024*8] = 512 KB (hi fragments only)
#define OFF_KEYS   1351680   // u64[65536] = 512 KB (fixup argmin keys)
#define OFF_WT     1875968   // float[256*1024] = 1 MB (W transposed [d][k])

// ---- numpy pairwise fp32 sum-of-squares emulation (contract off!) ----
__device__ __forceinline__ float pw128_sq(const float4* p) {
#pragma clang fp contract(off)
    float4 q0 = p[0], q1 = p[1];
    float r0 = q0.x * q0.x, r1 = q0.y * q0.y, r2 = q0.z * q0.z, r3 = q0.w * q0.w;
    float r4 = q1.x * q1.x, r5 = q1.y * q1.y, r6 = q1.z * q1.z, r7 = q1.w * q1.w;
    for (int i = 1; i < 16; ++i) {
        float4 u0 = p[2 * i], u1 = p[2 * i + 1];
        r0 = r0 + u0.x * u0.x; r1 = r1 + u0.y * u0.y;
        r2 = r2 + u0.z * u0.z; r3 = r3 + u0.w * u0.w;
        r4 = r4 + u1.x * u1.x; r5 = r5 + u1.y * u1.y;
        r6 = r6 + u1.z * u1.z; r7 = r7 + u1.w * u1.w;
    }
    return ((r0 + r1) + (r2 + r3)) + ((r4 + r5) + (r6 + r7));
}
// identical op order, source elements are doubles that round-trip exactly to fp32
__device__ __forceinline__ float pw128_sq_lds(const double* p) {
#pragma clang fp contract(off)
    float r[8];
    #pragma unroll
    for (int j = 0; j < 8; ++j) { float x = (float)p[j]; r[j] = x * x; }
    for (int i = 1; i < 16; ++i) {
        #pragma unroll
        for (int j = 0; j < 8; ++j) { float x = (float)p[8 * i + j]; r[j] = r[j] + x * x; }
    }
    return ((r[0] + r[1]) + (r[2] + r[3])) + ((r[4] + r[5]) + (r[6] + r[7]));
}
__device__ __forceinline__ float rownorm_np(const float* row) {
#pragma clang fp contract(off)
    float s0 = pw128_sq((const float4*)row);
    float s1 = pw128_sq((const float4*)(row + 128));
    return s0 + s1;
}
__device__ __forceinline__ float np_dist(float A, float m, float Ck) {
#pragma clang fp contract(off)
    float Bv = 2.0f * m;
    float t  = A - Bv;
    return t + Ck;
}
__device__ __forceinline__ unsigned short bf16_rne(float x) {
    unsigned u = __float_as_uint(x);
    unsigned r = u + 0x7fff + ((u >> 16) & 1);
    return (unsigned short)(r >> 16);
}
__device__ __forceinline__ float bf16_tof(unsigned short h) {
    return __uint_as_float(((unsigned)h) << 16);
}

// ---------------- K1: prep — w-norms + wfrag + wT (e-norms eliminated) ----------------
#define PRS 260
__global__ __launch_bounds__(256) void k_prep(
        const float* __restrict__ wg,
        float* __restrict__ wn,
        unsigned short* __restrict__ wfrag, float* __restrict__ wt) {
    __shared__ __align__(16) float es[32 * PRS];
    const int tid = threadIdx.x;
    const int bx  = blockIdx.x;
    if (bx < 4) {
        // ---- w-norms: thread-per-row (1024 rows total) ----
        int row = bx * 256 + tid;
        wn[row] = rownorm_np(wg + (size_t)row * D_DIM);
    } else if (bx < 132) {
        // ---- wfrag: bf16-hi fragments only, layout [kc][col][8] ----
        int t = (bx - 4) * 256 + tid;        // 0..32767
        int col = t >> 5, kc = t & 31;
        const float4* src = (const float4*)(wg + (size_t)col * D_DIM + kc * 8);
        float4 v0 = src[0], v1 = src[1];
        const float a[8] = {v0.x, v0.y, v0.z, v0.w, v1.x, v1.y, v1.z, v1.w};
        short8 h;
        #pragma unroll
        for (int i = 0; i < 8; ++i) h[i] = (short)bf16_rne(a[i]);
        *(short8*)(wfrag + ((size_t)kc * 1024 + col) * 8) = h;
    } else {
        // ---- wT: float transpose [d][k], 32 codes per block via LDS ----
        float (*tw)[PRS] = (float(*)[PRS])es;   // [32][260]
        const int cb = bx - 132;                // 0..31
        const int c0 = cb * 32;
        #pragma unroll
        for (int it = 0; it < 8; ++it) {
            int idx = it * 256 + tid;           // float4 index
            int code = idx >> 6, f4 = idx & 63;
            *(float4*)&tw[code][f4 * 4] =
                *(const float4*)(wg + (size_t)(c0 + code) * D_DIM + f4 * 4);
        }
        __syncthreads();
        const int j = tid & 31, dg = tid >> 5;  // dg 0..7
        #pragma unroll
        for (int dd = 0; dd < 32; ++dd) {
            int d = dd * 8 + dg;
            wt[(size_t)d * K_CB + c0 + j] = tw[j][d];
        }
    }
}

// ---------------- K2: MFMA split-2 distance — 16 rows/wave, full col sweep ----------------
// grid(1024): block = 64 rows; wave = 16 rows; 16 col-phases of 64 codes
// launch_bounds(256,2): VGPR pressure limit 128 >= ~115 need -> NO SPILL.
// ((256,4) made the allocator target 64 VGPRs and spill the A fragments:
//  41 MB scratch writes, per-phase reloads -> MfmaUtil capped at 26%.)
__global__ __launch_bounds__(256, 2) void k_dist(
        const float* __restrict__ eg, const unsigned short* __restrict__ wfrag,
        const float* __restrict__ wn,
        int* __restrict__ idx_ws, int* __restrict__ fixlist, int* __restrict__ fixcnt) {
    __shared__ __align__(16) unsigned short Bs[32 * BLINE];
    __shared__ float wnS[K_CB];
    const int tid  = threadIdx.x;
    const int lane = tid & 63;
    const int wv   = tid >> 6;
    const int q    = lane >> 4;
    const int m15  = lane & 15;
    const int waveRow = blockIdx.x * 64 + wv * 16;

    // ---- wn -> LDS once (covered by first top-of-loop barrier) ----
    #pragma unroll
    for (int i = 0; i < 4; ++i) wnS[tid + i * 256] = wn[tid + i * 256];

    // ---- A fragments: load fp32, split hi/lo, keep in registers for whole kernel ----
    short8 afh[8], afl[8];
    {
        const float* rowp = eg + (size_t)(waveRow + m15) * D_DIM + q * 8;
        #pragma unroll
        for (int win = 0; win < 8; ++win) {
            const float4* pa = (const float4*)(rowp + win * 32);
            float4 x0 = pa[0], x1 = pa[1];
            const float a[8] = {x0.x, x0.y, x0.z, x0.w, x1.x, x1.y, x1.z, x1.w};
            short8 h, l;
            #pragma unroll
            for (int i = 0; i < 8; ++i) {
                unsigned short hh = bf16_rne(a[i]);
                h[i] = (short)hh;
                l[i] = (short)bf16_rne(a[i] - bf16_tof(hh));
            }
            afh[win] = h;
            afl[win] = l;
        }
    }

    float best[4], sec[4];
    int bidx[4];
    #pragma unroll
    for (int s = 0; s < 4; ++s) { best[s] = 3.4e38f; sec[s] = 3.4e38f; bidx[s] = 0; }

    for (int cb = 0; cb < 16; ++cb) {
        __syncthreads();   // Bs reuse guard (also publishes wnS on first pass)
        // stage this phase's B tile: 32 lines of 1 KB via global_load_lds, 8 lines/wave
        #pragma unroll
        for (int t = 0; t < 8; ++t) {
            int L = wv * 8 + t;   // = kc 0..31
            const unsigned short* src = wfrag + ((size_t)L * 1024 + cb * 64) * 8 + lane * 8;
            __builtin_amdgcn_global_load_lds(
                (const __attribute__((address_space(1))) unsigned int*)src,
                (__attribute__((address_space(3))) unsigned int*)&Bs[L * BLINE],
                16, 0, 0);
        }
        __syncthreads();   // compiler emits vmcnt(0) drain before barrier

        floatx4 acc[4];
        #pragma unroll
        for (int nt = 0; nt < 4; ++nt)
            acc[nt] = (floatx4){0.f, 0.f, 0.f, 0.f};

        #pragma unroll
        for (int nt = 0; nt < 4; ++nt) {
            #pragma unroll
            for (int win = 0; win < 8; ++win) {
                int kc = win * 4 + q;
                short8 bfh = *(short8*)&Bs[kc * BLINE + (nt * 16 + m15) * 8];
                acc[nt] = __builtin_amdgcn_mfma_f32_16x16x32_bf16(afh[win], bfh, acc[nt], 0, 0, 0);
                acc[nt] = __builtin_amdgcn_mfma_f32_16x16x32_bf16(afl[win], bfh, acc[nt], 0, 0, 0);
            }
        }
        // fold into running top-2 (cols ascend with cb,nt -> first-min kept)
        #pragma unroll
        for (int nt = 0; nt < 4; ++nt) {
            int col = cb * 64 + nt * 16 + m15;
            float Ck = wnS[col];
            #pragma unroll
            for (int reg = 0; reg < 4; ++reg) {
                float d = __builtin_fmaf(-2.0f, acc[nt][reg], Ck);
                bool lt = d < best[reg];
                sec[reg]  = __builtin_amdgcn_fmed3f(d, best[reg], sec[reg]);
                best[reg] = fminf(d, best[reg]);
                bidx[reg] = lt ? col : bidx[reg];
            }
        }
    }

    // butterfly top-2 merge across the 16 m15 lanes (rows live per (q,reg))
    #pragma unroll
    for (int s = 0; s < 4; ++s) {
        float b = best[s], se = sec[s];
        int ix = bidx[s];
        #pragma unroll
        for (int m = 1; m < 16; m <<= 1) {
            float bo = __shfl_xor(b, m, 64);
            float so = __shfl_xor(se, m, 64);
            int   io = __shfl_xor(ix, m, 64);
            float ns = fminf(fminf(se, so), fmaxf(b, bo));
            if (bo < b || (bo == b && io < ix)) { b = bo; ix = io; }
            se = ns;
        }
        if (m15 == 0) {
            int row = waveRow + q * 4 + s;
            idx_ws[row] = ix;
            if (se - b < TAU) {
                int p = atomicAdd(fixcnt, 1);
                fixlist[p] = row;
            }
        }
    }
}

// ---------------- K3: fp64 np-exact recheck — register-blocked 4x4 ----------------
// tile = (group of 8 rows, chunk of 512 codes); thread = 4 rows x 4 codes.
// e rows broadcast from LDS (wave-uniform addr -> conflict-free); W read via
// wT[d][k] so lanes load consecutive float4s (coalesced, L2-resident).
// row-norms computed in-kernel from the LDS copy (bit-identical to rownorm_np:
// fp32<->fp64 round trip is exact, op order replicated).
#define FG_ROWS 8
__global__ __launch_bounds__(256) void k_fixup(
        const float* __restrict__ eg, const float* __restrict__ wt,
        const float* __restrict__ wnorm,
        const int* __restrict__ fixlist, const int* __restrict__ fixcnt,
        unsigned long long* __restrict__ keys) {
    __shared__ double xs[FG_ROWS][D_DIM];    // 16 KB
    __shared__ float AnS[FG_ROWS];
    const int tid = threadIdx.x;
    const int cnt = *fixcnt;
    if (cnt == 0) return;
    const int ngroups = (cnt + FG_ROWS - 1) / FG_ROWS;
    const int ntiles  = ngroups * 2;
    const int rowg = tid >> 7;               // 0,1 -> rows 4*rowg..4*rowg+3
    const int cg   = tid & 127;              // code group (4 codes each)
    for (int t = blockIdx.x; t < ntiles; t += gridDim.x) {
        const int g     = t >> 1;
        const int chunk = t & 1;
        __syncthreads();   // xs/AnS reuse guard across grid-stride tiles
        int rows[FG_ROWS];
        #pragma unroll
        for (int i = 0; i < FG_ROWS; ++i) {
            int j = g * FG_ROWS + i;
            rows[i] = fixlist[j < cnt ? j : cnt - 1];
        }
        #pragma unroll
        for (int i = 0; i < FG_ROWS; ++i)
            xs[i][tid] = (double)eg[(size_t)rows[i] * D_DIM + tid];
        __syncthreads();

        // ---- row norms from LDS copy (numpy-pairwise-exact) ----
        if (tid < 16) {
            int row = tid >> 1, half = tid & 1;
            float s = pw128_sq_lds(&xs[row][half * 128]);
            float so = __shfl_xor(s, 1, 64);
            if (half == 0) AnS[row] = s + so;
        }

        const int c0 = chunk * 512 + cg * 4;
        float Cw[4];
        #pragma unroll
        for (int c = 0; c < 4; ++c) Cw[c] = wnorm[c0 + c];

        double s[4][4];
        #pragma unroll
        for (int r = 0; r < 4; ++r)
            #pragma unroll
            for (int c = 0; c < 4; ++c) s[r][c] = 0.0;

        #pragma unroll 2
        for (int d = 0; d < D_DIM; d += 2) {
            float4 wa = *(const float4*)(wt + (size_t)d * K_CB + c0);
            float4 wb = *(const float4*)(wt + (size_t)(d + 1) * K_CB + c0);
            double wad[4] = {(double)wa.x, (double)wa.y, (double)wa.z, (double)wa.w};
            double wbd[4] = {(double)wb.x, (double)wb.y, (double)wb.z, (double)wb.w};
            #pragma unroll
            for (int r = 0; r < 4; ++r) {
                double2 e2 = *(const double2*)&xs[rowg * 4 + r][d];
                #pragma unroll
                for (int c = 0; c < 4; ++c)
                    s[r][c] += e2.x * wad[c] + e2.y * wbd[c];
            }
        }
        __syncthreads();   // AnS ready for all threads

        #pragma unroll
        for (int r = 0; r < 4; ++r) {
            float An = AnS[rowg * 4 + r];
            unsigned long long key = 0xFFFFFFFFFFFFFFFFull;
            #pragma unroll
            for (int c = 0; c < 4; ++c) {
                float dq = np_dist(An, (float)s[r][c], Cw[c]);
                unsigned u = __float_as_uint(dq);
                unsigned key32 = u ^ (((unsigned)((int)u >> 31)) | 0x80000000u);
                unsigned long long kk =
                    ((unsigned long long)key32 << 32) | (unsigned)(c0 + c);
                key = kk < key ? kk : key;
            }
            #pragma unroll
            for (int m = 1; m < 64; m <<= 1) {
                unsigned long long o = __shfl_xor(key, m, 64);
                key = (o < key) ? o : key;
            }
            int j = g * FG_ROWS + rowg * 4 + r;
            if ((tid & 63) == 0 && j < cnt) atomicMin(&keys[j], key);
        }
    }
}

// ---------------- K3b: scatter fixup winners back into idx_ws ----------------
__global__ void k_fixscatter(const int* __restrict__ fixlist, const int* __restrict__ fixcnt,
                             const unsigned long long* __restrict__ keys,
                             int* __restrict__ idx_ws) {
    const int cnt = *fixcnt;
    for (int j = blockIdx.x * blockDim.x + threadIdx.x; j < cnt;
         j += gridDim.x * blockDim.x)
        idx_ws[fixlist[j]] = (int)(keys[j] & 0xFFFFFFFFull);
}

// ---------------- K4: gather + STE + loss partials + histogram (float4 vectorized) ----------------
__global__ void k_final(const float* __restrict__ eg, const float* __restrict__ wg,
                        const int* __restrict__ idx_ws, float* __restrict__ qout,
                        float* __restrict__ iout, int* __restrict__ hist,
                        double* __restrict__ partials) {
    const int tid  = threadIdx.x;
    const int sub  = tid >> 6;      // 0..3: row within quad
    const int lane = tid & 63;      // float4 column
    const int rowBase = blockIdx.x * 16;
    double acc = 0.0;
    #pragma unroll
    for (int g = 0; g < 4; ++g) {
        int row = rowBase + g * 4 + sub;
        int k = idx_ws[row];
        float4 ev = ((const float4*)(eg + (size_t)row * D_DIM))[lane];
        float4 wv = ((const float4*)(wg + (size_t)k   * D_DIM))[lane];
        float dx = wv.x - ev.x, dy = wv.y - ev.y, dz = wv.z - ev.z, dw = wv.w - ev.w;
        float4 qv = {ev.x + dx, ev.y + dy, ev.z + dz, ev.w + dw};
        ((float4*)(qout + (size_t)row * D_DIM))[lane] = qv;
        acc += (double)(dx * dx) + (double)(dy * dy)
             + (double)(dz * dz) + (double)(dw * dw);
        if (lane == 0) {
            iout[row] = (float)k;
            atomicAdd(&hist[k], 1);
        }
    }
    __shared__ double red[256];
    red[tid] = acc;
    __syncthreads();
    for (int st = 128; st > 0; st >>= 1) {
        if (tid < st) red[tid] += red[tid + st];
        __syncthreads();
    }
    if (tid == 0) partials[blockIdx.x] = red[0];
}

// ---------------- K5: scalars ----------------
__global__ void k_scalars(const int* __restrict__ hist, const double* __restrict__ partials,
                          float* __restrict__ sout) {
    const int tid = threadIdx.x;
    double s = 0.0;
    for (int j = tid; j < N_ROWS / 16; j += 256) s += partials[j];
    int m = 0;
    for (int j = tid; j < K_CB; j += 256) m = max(m, hist[j]);
    __shared__ double rs[256];
    __shared__ int    rm[256];
    rs[tid] = s; rm[tid] = m;
    __syncthreads();
    for (int st = 128; st > 0; st >>= 1) {
        if (tid < st) { rs[tid] += rs[tid + st]; rm[tid] = max(rm[tid], rm[tid + st]); }
        __syncthreads();
    }
    if (tid == 0) {
        sout[0] = (float)(rs[0] / (double)((size_t)N_ROWS * D_DIM));
        sout[1] = (float)rm[0] / 65536.0f;
    }
}

extern "C" void kernel_launch(void* const* d_in, const int* in_sizes, int n_in,
                              void* d_out, int out_size, void* d_ws, size_t ws_size,
                              hipStream_t stream) {
    const float* e = (const float*)d_in[0];
    const float* w = (const float*)d_in[1];
    float* out  = (float*)d_out;
    float* qout = out;
    float* iout = out + (size_t)N_ROWS * D_DIM;
    float* sout = iout + N_ROWS;

    char* ws = (char*)d_ws;
    float*  wn       = (float*) (ws + OFF_WN);
    int*    fixcnt   = (int*)   (ws + OFF_FIXCNT);
    int*    hist     = (int*)   (ws + OFF_HIST);
    int*    idxp     = (int*)   (ws + OFF_IDX);
    int*    list     = (int*)   (ws + OFF_LIST);
    double* partials = (double*)(ws + OFF_PART);
    unsigned short* wfrag = (unsigned short*)(ws + OFF_WFRAG);
    unsigned long long* keys = (unsigned long long*)(ws + OFF_KEYS);
    float*  wt       = (float*) (ws + OFF_WT);

    hipMemsetAsync(ws + OFF_FIXCNT, 0, 4352, stream);        // fixcnt + hist
    hipMemsetAsync(ws + OFF_KEYS, 0xFF, 524288, stream);     // keys = u64 max

    hipLaunchKernelGGL(k_prep,       dim3(164),         dim3(256), 0, stream, w, wn, wfrag, wt);
    hipLaunchKernelGGL(k_dist,       dim3(1024),        dim3(256), 0, stream, e, wfrag, wn, idxp, list, fixcnt);
    hipLaunchKernelGGL(k_fixup,      dim3(2048),        dim3(256), 0, stream, e, wt, wn, list, fixcnt, keys);
    hipLaunchKernelGGL(k_fixscatter, dim3(64),          dim3(256), 0, stream, list, fixcnt, keys, idxp);
    hipLaunchKernelGGL(k_final,      dim3(N_ROWS / 16), dim3(256), 0, stream, e, w, idxp, qout, iout, hist, partials);
    hipLaunchKernelGGL(k_scalars,    dim3(1),           dim3(256), 0, stream, hist, partials, sout);
}

// Round 6
// 314.700 us; speedup vs baseline: 1.2734x; 1.0012x over previous
//
#include <hip/hip_runtime.h>

typedef __attribute__((ext_vector_type(8))) short short8;
typedef __attribute__((ext_vector_type(4))) float floatx4;

#define N_ROWS 65536
#define K_CB   1024
#define D_DIM  256

// single-term distance (ah*bh): both residual terms dropped; combined error
// sigma ~3.8e-5 on distances; TAU widened to keep the same tail margin that
// passed at 2-term/3e-4 (absmax 0.0 rounds 1-5).
#define TAU 4.0e-4f
#define BLINE 520   // shorts per B LDS line (512 data + 8 pad = 1040 B)

// ws layout (bytes) — ws_size >= 14 MB proven on this harness
#define OFF_WN     262144    // float[1024]
#define OFF_FIXCNT 266240    // int
#define OFF_HIST   266496    // int[1024]
#define OFF_IDX    270592    // int[65536]
#define OFF_LIST   532736    // int[65536]
#define OFF_PART   794880    // double[4096]
#define OFF_WFRAG  827392    // ushort[32*1024*8] = 512 KB (hi fragments only)
#define OFF_KEYS   1351680   // u64[65536] = 512 KB (fixup argmin keys)
#define OFF_WT     1875968   // float[256*1024] = 1 MB (W transposed [d][k])

// ---- numpy pairwise fp32 sum-of-squares emulation (contract off!) ----
__device__ __forceinline__ float pw128_sq(const float4* p) {
#pragma clang fp contract(off)
    float4 q0 = p[0], q1 = p[1];
    float r0 = q0.x * q0.x, r1 = q0.y * q0.y, r2 = q0.z * q0.z, r3 = q0.w * q0.w;
    float r4 = q1.x * q1.x, r5 = q1.y * q1.y, r6 = q1.z * q1.z, r7 = q1.w * q1.w;
    for (int i = 1; i < 16; ++i) {
        float4 u0 = p[2 * i], u1 = p[2 * i + 1];
        r0 = r0 + u0.x * u0.x; r1 = r1 + u0.y * u0.y;
        r2 = r2 + u0.z * u0.z; r3 = r3 + u0.w * u0.w;
        r4 = r4 + u1.x * u1.x; r5 = r5 + u1.y * u1.y;
        r6 = r6 + u1.z * u1.z; r7 = r7 + u1.w * u1.w;
    }
    return ((r0 + r1) + (r2 + r3)) + ((r4 + r5) + (r6 + r7));
}
// identical op order, source elements are doubles that round-trip exactly to fp32
__device__ __forceinline__ float pw128_sq_lds(const double* p) {
#pragma clang fp contract(off)
    float r[8];
    #pragma unroll
    for (int j = 0; j < 8; ++j) { float x = (float)p[j]; r[j] = x * x; }
    for (int i = 1; i < 16; ++i) {
        #pragma unroll
        for (int j = 0; j < 8; ++j) { float x = (float)p[8 * i + j]; r[j] = r[j] + x * x; }
    }
    return ((r[0] + r[1]) + (r[2] + r[3])) + ((r[4] + r[5]) + (r[6] + r[7]));
}
__device__ __forceinline__ float rownorm_np(const float* row) {
#pragma clang fp contract(off)
    float s0 = pw128_sq((const float4*)row);
    float s1 = pw128_sq((const float4*)(row + 128));
    return s0 + s1;
}
__device__ __forceinline__ float np_dist(float A, float m, float Ck) {
#pragma clang fp contract(off)
    float Bv = 2.0f * m;
    float t  = A - Bv;
    return t + Ck;
}
__device__ __forceinline__ unsigned short bf16_rne(float x) {
    unsigned u = __float_as_uint(x);
    unsigned r = u + 0x7fff + ((u >> 16) & 1);
    return (unsigned short)(r >> 16);
}

// ---------------- K1: prep — w-norms + wfrag + wT ----------------
#define PRS 260
__global__ __launch_bounds__(256) void k_prep(
        const float* __restrict__ wg,
        float* __restrict__ wn,
        unsigned short* __restrict__ wfrag, float* __restrict__ wt) {
    __shared__ __align__(16) float es[32 * PRS];
    const int tid = threadIdx.x;
    const int bx  = blockIdx.x;
    if (bx < 4) {
        // ---- w-norms: thread-per-row (1024 rows total) ----
        int row = bx * 256 + tid;
        wn[row] = rownorm_np(wg + (size_t)row * D_DIM);
    } else if (bx < 132) {
        // ---- wfrag: bf16-hi fragments only, layout [kc][col][8] ----
        int t = (bx - 4) * 256 + tid;        // 0..32767
        int col = t >> 5, kc = t & 31;
        const float4* src = (const float4*)(wg + (size_t)col * D_DIM + kc * 8);
        float4 v0 = src[0], v1 = src[1];
        const float a[8] = {v0.x, v0.y, v0.z, v0.w, v1.x, v1.y, v1.z, v1.w};
        short8 h;
        #pragma unroll
        for (int i = 0; i < 8; ++i) h[i] = (short)bf16_rne(a[i]);
        *(short8*)(wfrag + ((size_t)kc * 1024 + col) * 8) = h;
    } else {
        // ---- wT: float transpose [d][k], 32 codes per block via LDS ----
        float (*tw)[PRS] = (float(*)[PRS])es;   // [32][260]
        const int cb = bx - 132;                // 0..31
        const int c0 = cb * 32;
        #pragma unroll
        for (int it = 0; it < 8; ++it) {
            int idx = it * 256 + tid;           // float4 index
            int code = idx >> 6, f4 = idx & 63;
            *(float4*)&tw[code][f4 * 4] =
                *(const float4*)(wg + (size_t)(c0 + code) * D_DIM + f4 * 4);
        }
        __syncthreads();
        const int j = tid & 31, dg = tid >> 5;  // dg 0..7
        #pragma unroll
        for (int dd = 0; dd < 32; ++dd) {
            int d = dd * 8 + dg;
            wt[(size_t)d * K_CB + c0 + j] = tw[j][d];
        }
    }
}

// ---------------- K2: MFMA single-term distance — 32 rows/wave ----------------
// grid(512): block = 128 rows (4 waves x 32); 16 col-phases of 64 codes.
// Round-5 lesson: kernel is LDS-read-pipe-bound (8192 b128/CU x 12cyc = 41us
// + 14us conflicts), NOT spill/MFMA-bound. Fix: each bfh read now feeds 2
// MFMAs covering 32 rows (B LDS traffic halved) and single-term halves the
// MFMA work. afh only: ~115 VGPR, no spill at (256,2).
__global__ __launch_bounds__(256, 2) void k_dist(
        const float* __restrict__ eg, const unsigned short* __restrict__ wfrag,
        const float* __restrict__ wn,
        int* __restrict__ idx_ws, int* __restrict__ fixlist, int* __restrict__ fixcnt) {
    __shared__ __align__(16) unsigned short Bs[32 * BLINE];
    __shared__ float wnS[K_CB];
    const int tid  = threadIdx.x;
    const int lane = tid & 63;
    const int wv   = tid >> 6;
    const int q    = lane >> 4;
    const int m15  = lane & 15;
    const int waveRow = blockIdx.x * 128 + wv * 32;

    // ---- wn -> LDS once (covered by first top-of-loop barrier) ----
    #pragma unroll
    for (int i = 0; i < 4; ++i) wnS[tid + i * 256] = wn[tid + i * 256];

    // ---- A fragments: bf16-hi only, 2 row-tiles, kept in regs whole kernel ----
    short8 afh0[8], afh1[8];
    #pragma unroll
    for (int mt = 0; mt < 2; ++mt) {
        const float* rowp = eg + (size_t)(waveRow + mt * 16 + m15) * D_DIM + q * 8;
        #pragma unroll
        for (int win = 0; win < 8; ++win) {
            const float4* pa = (const float4*)(rowp + win * 32);
            float4 x0 = pa[0], x1 = pa[1];
            const float a[8] = {x0.x, x0.y, x0.z, x0.w, x1.x, x1.y, x1.z, x1.w};
            short8 h;
            #pragma unroll
            for (int i = 0; i < 8; ++i) h[i] = (short)bf16_rne(a[i]);
            if (mt == 0) afh0[win] = h; else afh1[win] = h;
        }
    }

    float best[8], sec[8];
    int bidx[8];
    #pragma unroll
    for (int s = 0; s < 8; ++s) { best[s] = 3.4e38f; sec[s] = 3.4e38f; bidx[s] = 0; }

    for (int cb = 0; cb < 16; ++cb) {
        __syncthreads();   // Bs reuse guard (also publishes wnS on first pass)
        // stage this phase's B tile: 32 lines of 1 KB via global_load_lds, 8/wave
        #pragma unroll
        for (int t = 0; t < 8; ++t) {
            int L = wv * 8 + t;   // = kc 0..31
            const unsigned short* src = wfrag + ((size_t)L * 1024 + cb * 64) * 8 + lane * 8;
            __builtin_amdgcn_global_load_lds(
                (const __attribute__((address_space(1))) unsigned int*)src,
                (__attribute__((address_space(3))) unsigned int*)&Bs[L * BLINE],
                16, 0, 0);
        }
        __syncthreads();   // vmcnt(0) drain before barrier

        #pragma unroll
        for (int nt = 0; nt < 4; ++nt) {
            floatx4 acc0 = (floatx4){0.f, 0.f, 0.f, 0.f};
            floatx4 acc1 = (floatx4){0.f, 0.f, 0.f, 0.f};
            #pragma unroll
            for (int win = 0; win < 8; ++win) {
                int kc = win * 4 + q;
                short8 bfh = *(short8*)&Bs[kc * BLINE + (nt * 16 + m15) * 8];
                acc0 = __builtin_amdgcn_mfma_f32_16x16x32_bf16(afh0[win], bfh, acc0, 0, 0, 0);
                acc1 = __builtin_amdgcn_mfma_f32_16x16x32_bf16(afh1[win], bfh, acc1, 0, 0, 0);
            }
            // fold into running top-2 (cols ascend with cb,nt -> first-min kept)
            int col = cb * 64 + nt * 16 + m15;
            float Ck = wnS[col];
            #pragma unroll
            for (int reg = 0; reg < 4; ++reg) {
                float d0 = __builtin_fmaf(-2.0f, acc0[reg], Ck);
                bool lt0 = d0 < best[reg];
                sec[reg]  = __builtin_amdgcn_fmed3f(d0, best[reg], sec[reg]);
                best[reg] = fminf(d0, best[reg]);
                bidx[reg] = lt0 ? col : bidx[reg];
                float d1 = __builtin_fmaf(-2.0f, acc1[reg], Ck);
                int s1 = 4 + reg;
                bool lt1 = d1 < best[s1];
                sec[s1]  = __builtin_amdgcn_fmed3f(d1, best[s1], sec[s1]);
                best[s1] = fminf(d1, best[s1]);
                bidx[s1] = lt1 ? col : bidx[s1];
            }
        }
    }

    // butterfly top-2 merge across the 16 m15 lanes (rows live per (q,mt,reg))
    #pragma unroll
    for (int s = 0; s < 8; ++s) {
        float b = best[s], se = sec[s];
        int ix = bidx[s];
        #pragma unroll
        for (int m = 1; m < 16; m <<= 1) {
            float bo = __shfl_xor(b, m, 64);
            float so = __shfl_xor(se, m, 64);
            int   io = __shfl_xor(ix, m, 64);
            float ns = fminf(fminf(se, so), fmaxf(b, bo));
            if (bo < b || (bo == b && io < ix)) { b = bo; ix = io; }
            se = ns;
        }
        if (m15 == 0) {
            int row = waveRow + (s >> 2) * 16 + q * 4 + (s & 3);
            idx_ws[row] = ix;
            if (se - b < TAU) {
                int p = atomicAdd(fixcnt, 1);
                fixlist[p] = row;
            }
        }
    }
}

// ---------------- K3: fp64 np-exact recheck — register-blocked 4x4 ----------------
#define FG_ROWS 8
__global__ __launch_bounds__(256) void k_fixup(
        const float* __restrict__ eg, const float* __restrict__ wt,
        const float* __restrict__ wnorm,
        const int* __restrict__ fixlist, const int* __restrict__ fixcnt,
        unsigned long long* __restrict__ keys) {
    __shared__ double xs[FG_ROWS][D_DIM];    // 16 KB
    __shared__ float AnS[FG_ROWS];
    const int tid = threadIdx.x;
    const int cnt = *fixcnt;
    if (cnt == 0) return;
    const int ngroups = (cnt + FG_ROWS - 1) / FG_ROWS;
    const int ntiles  = ngroups * 2;
    const int rowg = tid >> 7;               // 0,1 -> rows 4*rowg..4*rowg+3
    const int cg   = tid & 127;              // code group (4 codes each)
    for (int t = blockIdx.x; t < ntiles; t += gridDim.x) {
        const int g     = t >> 1;
        const int chunk = t & 1;
        __syncthreads();   // xs/AnS reuse guard across grid-stride tiles
        int rows[FG_ROWS];
        #pragma unroll
        for (int i = 0; i < FG_ROWS; ++i) {
            int j = g * FG_ROWS + i;
            rows[i] = fixlist[j < cnt ? j : cnt - 1];
        }
        #pragma unroll
        for (int i = 0; i < FG_ROWS; ++i)
            xs[i][tid] = (double)eg[(size_t)rows[i] * D_DIM + tid];
        __syncthreads();

        // ---- row norms from LDS copy (numpy-pairwise-exact) ----
        if (tid < 16) {
            int row = tid >> 1, half = tid & 1;
            float s = pw128_sq_lds(&xs[row][half * 128]);
            float so = __shfl_xor(s, 1, 64);
            if (half == 0) AnS[row] = s + so;
        }

        const int c0 = chunk * 512 + cg * 4;
        float Cw[4];
        #pragma unroll
        for (int c = 0; c < 4; ++c) Cw[c] = wnorm[c0 + c];

        double s[4][4];
        #pragma unroll
        for (int r = 0; r < 4; ++r)
            #pragma unroll
            for (int c = 0; c < 4; ++c) s[r][c] = 0.0;

        #pragma unroll 2
        for (int d = 0; d < D_DIM; d += 2) {
            float4 wa = *(const float4*)(wt + (size_t)d * K_CB + c0);
            float4 wb = *(const float4*)(wt + (size_t)(d + 1) * K_CB + c0);
            double wad[4] = {(double)wa.x, (double)wa.y, (double)wa.z, (double)wa.w};
            double wbd[4] = {(double)wb.x, (double)wb.y, (double)wb.z, (double)wb.w};
            #pragma unroll
            for (int r = 0; r < 4; ++r) {
                double2 e2 = *(const double2*)&xs[rowg * 4 + r][d];
                #pragma unroll
                for (int c = 0; c < 4; ++c)
                    s[r][c] += e2.x * wad[c] + e2.y * wbd[c];
            }
        }
        __syncthreads();   // AnS ready for all threads

        #pragma unroll
        for (int r = 0; r < 4; ++r) {
            float An = AnS[rowg * 4 + r];
            unsigned long long key = 0xFFFFFFFFFFFFFFFFull;
            #pragma unroll
            for (int c = 0; c < 4; ++c) {
                float dq = np_dist(An, (float)s[r][c], Cw[c]);
                unsigned u = __float_as_uint(dq);
                unsigned key32 = u ^ (((unsigned)((int)u >> 31)) | 0x80000000u);
                unsigned long long kk =
                    ((unsigned long long)key32 << 32) | (unsigned)(c0 + c);
                key = kk < key ? kk : key;
            }
            #pragma unroll
            for (int m = 1; m < 64; m <<= 1) {
                unsigned long long o = __shfl_xor(key, m, 64);
                key = (o < key) ? o : key;
            }
            int j = g * FG_ROWS + rowg * 4 + r;
            if ((tid & 63) == 0 && j < cnt) atomicMin(&keys[j], key);
        }
    }
}

// ---------------- K3b: scatter fixup winners back into idx_ws ----------------
__global__ void k_fixscatter(const int* __restrict__ fixlist, const int* __restrict__ fixcnt,
                             const unsigned long long* __restrict__ keys,
                             int* __restrict__ idx_ws) {
    const int cnt = *fixcnt;
    for (int j = blockIdx.x * blockDim.x + threadIdx.x; j < cnt;
         j += gridDim.x * blockDim.x)
        idx_ws[fixlist[j]] = (int)(keys[j] & 0xFFFFFFFFull);
}

// ---------------- K4: gather + STE + loss partials + histogram (float4 vectorized) ----------------
__global__ void k_final(const float* __restrict__ eg, const float* __restrict__ wg,
                        const int* __restrict__ idx_ws, float* __restrict__ qout,
                        float* __restrict__ iout, int* __restrict__ hist,
                        double* __restrict__ partials) {
    const int tid  = threadIdx.x;
    const int sub  = tid >> 6;      // 0..3: row within quad
    const int lane = tid & 63;      // float4 column
    const int rowBase = blockIdx.x * 16;
    double acc = 0.0;
    #pragma unroll
    for (int g = 0; g < 4; ++g) {
        int row = rowBase + g * 4 + sub;
        int k = idx_ws[row];
        float4 ev = ((const float4*)(eg + (size_t)row * D_DIM))[lane];
        float4 wv = ((const float4*)(wg + (size_t)k   * D_DIM))[lane];
        float dx = wv.x - ev.x, dy = wv.y - ev.y, dz = wv.z - ev.z, dw = wv.w - ev.w;
        float4 qv = {ev.x + dx, ev.y + dy, ev.z + dz, ev.w + dw};
        ((float4*)(qout + (size_t)row * D_DIM))[lane] = qv;
        acc += (double)(dx * dx) + (double)(dy * dy)
             + (double)(dz * dz) + (double)(dw * dw);
        if (lane == 0) {
            iout[row] = (float)k;
            atomicAdd(&hist[k], 1);
        }
    }
    __shared__ double red[256];
    red[tid] = acc;
    __syncthreads();
    for (int st = 128; st > 0; st >>= 1) {
        if (tid < st) red[tid] += red[tid + st];
        __syncthreads();
    }
    if (tid == 0) partials[blockIdx.x] = red[0];
}

// ---------------- K5: scalars ----------------
__global__ void k_scalars(const int* __restrict__ hist, const double* __restrict__ partials,
                          float* __restrict__ sout) {
    const int tid = threadIdx.x;
    double s = 0.0;
    for (int j = tid; j < N_ROWS / 16; j += 256) s += partials[j];
    int m = 0;
    for (int j = tid; j < K_CB; j += 256) m = max(m, hist[j]);
    __shared__ double rs[256];
    __shared__ int    rm[256];
    rs[tid] = s; rm[tid] = m;
    __syncthreads();
    for (int st = 128; st > 0; st >>= 1) {
        if (tid < st) { rs[tid] += rs[tid + st]; rm[tid] = max(rm[tid], rm[tid + st]); }
        __syncthreads();
    }
    if (tid == 0) {
        sout[0] = (float)(rs[0] / (double)((size_t)N_ROWS * D_DIM));
        sout[1] = (float)rm[0] / 65536.0f;
    }
}

extern "C" void kernel_launch(void* const* d_in, const int* in_sizes, int n_in,
                              void* d_out, int out_size, void* d_ws, size_t ws_size,
                              hipStream_t stream) {
    const float* e = (const float*)d_in[0];
    const float* w = (const float*)d_in[1];
    float* out  = (float*)d_out;
    float* qout = out;
    float* iout = out + (size_t)N_ROWS * D_DIM;
    float* sout = iout + N_ROWS;

    char* ws = (char*)d_ws;
    float*  wn       = (float*) (ws + OFF_WN);
    int*    fixcnt   = (int*)   (ws + OFF_FIXCNT);
    int*    hist     = (int*)   (ws + OFF_HIST);
    int*    idxp     = (int*)   (ws + OFF_IDX);
    int*    list     = (int*)   (ws + OFF_LIST);
    double* partials = (double*)(ws + OFF_PART);
    unsigned short* wfrag = (unsigned short*)(ws + OFF_WFRAG);
    unsigned long long* keys = (unsigned long long*)(ws + OFF_KEYS);
    float*  wt       = (float*) (ws + OFF_WT);

    hipMemsetAsync(ws + OFF_FIXCNT, 0, 4352, stream);        // fixcnt + hist
    hipMemsetAsync(ws + OFF_KEYS, 0xFF, 524288, stream);     // keys = u64 max

    hipLaunchKernelGGL(k_prep,       dim3(164),         dim3(256), 0, stream, w, wn, wfrag, wt);
    hipLaunchKernelGGL(k_dist,       dim3(512),         dim3(256), 0, stream, e, wfrag, wn, idxp, list, fixcnt);
    hipLaunchKernelGGL(k_fixup,      dim3(2048),        dim3(256), 0, stream, e, wt, wn, list, fixcnt, keys);
    hipLaunchKernelGGL(k_fixscatter, dim3(64),          dim3(256), 0, stream, list, fixcnt, keys, idxp);
    hipLaunchKernelGGL(k_final,      dim3(N_ROWS / 16), dim3(256), 0, stream, e, w, idxp, qout, iout, hist, partials);
    hipLaunchKernelGGL(k_scalars,    dim3(1),           dim3(256), 0, stream, hist, partials, sout);
}

// Round 7
// 296.926 us; speedup vs baseline: 1.3497x; 1.0599x over previous
//
#include <hip/hip_runtime.h>

typedef __attribute__((ext_vector_type(8))) short short8;
typedef __attribute__((ext_vector_type(4))) float floatx4;

#define N_ROWS 65536
#define K_CB   1024
#define D_DIM  256

// single-term distance (ah*bh): residual terms dropped; error folded into the
// recheck band (R6-proven numerics).
#define TAU 4.0e-4f
#define BLINE 520   // shorts per B LDS line (512 data + 8 pad = 1040 B)

// ws layout (bytes) — ws_size >= 14 MB proven on this harness
#define OFF_WN     262144    // float[1024]
#define OFF_FIXCNT 266240    // int
#define OFF_HIST   266496    // int[1024]
#define OFF_IDX    270592    // int[65536]
#define OFF_LIST   532736    // int[65536]
#define OFF_PART   794880    // double[4096]
#define OFF_WFRAG  827392    // ushort[32*1024*8] = 512 KB (hi fragments only)
#define OFF_KEYS   1351680   // u64[65536] = 512 KB (fixup argmin keys)
#define OFF_WT     1875968   // float[256*1024] = 1 MB (W transposed [d][k])

// ---- numpy pairwise fp32 sum-of-squares emulation (contract off!) ----
__device__ __forceinline__ float pw128_sq(const float4* p) {
#pragma clang fp contract(off)
    float4 q0 = p[0], q1 = p[1];
    float r0 = q0.x * q0.x, r1 = q0.y * q0.y, r2 = q0.z * q0.z, r3 = q0.w * q0.w;
    float r4 = q1.x * q1.x, r5 = q1.y * q1.y, r6 = q1.z * q1.z, r7 = q1.w * q1.w;
    for (int i = 1; i < 16; ++i) {
        float4 u0 = p[2 * i], u1 = p[2 * i + 1];
        r0 = r0 + u0.x * u0.x; r1 = r1 + u0.y * u0.y;
        r2 = r2 + u0.z * u0.z; r3 = r3 + u0.w * u0.w;
        r4 = r4 + u1.x * u1.x; r5 = r5 + u1.y * u1.y;
        r6 = r6 + u1.z * u1.z; r7 = r7 + u1.w * u1.w;
    }
    return ((r0 + r1) + (r2 + r3)) + ((r4 + r5) + (r6 + r7));
}
__device__ __forceinline__ float rownorm_np(const float* row) {
#pragma clang fp contract(off)
    float s0 = pw128_sq((const float4*)row);
    float s1 = pw128_sq((const float4*)(row + 128));
    return s0 + s1;
}
__device__ __forceinline__ float np_dist(float A, float m, float Ck) {
#pragma clang fp contract(off)
    float Bv = 2.0f * m;
    float t  = A - Bv;
    return t + Ck;
}
__device__ __forceinline__ unsigned short bf16_rne(float x) {
    unsigned u = __float_as_uint(x);
    unsigned r = u + 0x7fff + ((u >> 16) & 1);
    return (unsigned short)(r >> 16);
}
__device__ __forceinline__ unsigned long long dist_key(float d, int idx) {
    unsigned u = __float_as_uint(d);
    unsigned k32 = u ^ (((unsigned)((int)u >> 31)) | 0x80000000u);
    return ((unsigned long long)k32 << 32) | (unsigned)idx;
}

// ---------------- K1: prep — w-norms + wfrag + wT ----------------
#define PRS 260
__global__ __launch_bounds__(256) void k_prep(
        const float* __restrict__ wg,
        float* __restrict__ wn,
        unsigned short* __restrict__ wfrag, float* __restrict__ wt) {
    __shared__ __align__(16) float es[32 * PRS];
    const int tid = threadIdx.x;
    const int bx  = blockIdx.x;
    if (bx < 4) {
        int row = bx * 256 + tid;
        wn[row] = rownorm_np(wg + (size_t)row * D_DIM);
    } else if (bx < 132) {
        // ---- wfrag: bf16-hi fragments only, layout [kc][col][8] ----
        int t = (bx - 4) * 256 + tid;        // 0..32767
        int col = t >> 5, kc = t & 31;
        const float4* src = (const float4*)(wg + (size_t)col * D_DIM + kc * 8);
        float4 v0 = src[0], v1 = src[1];
        const float a[8] = {v0.x, v0.y, v0.z, v0.w, v1.x, v1.y, v1.z, v1.w};
        short8 h;
        #pragma unroll
        for (int i = 0; i < 8; ++i) h[i] = (short)bf16_rne(a[i]);
        *(short8*)(wfrag + ((size_t)kc * 1024 + col) * 8) = h;
    } else {
        // ---- wT: float transpose [d][k], 32 codes per block via LDS ----
        float (*tw)[PRS] = (float(*)[PRS])es;   // [32][260]
        const int cb = bx - 132;                // 0..31
        const int c0 = cb * 32;
        #pragma unroll
        for (int it = 0; it < 8; ++it) {
            int idx = it * 256 + tid;           // float4 index
            int code = idx >> 6, f4 = idx & 63;
            *(float4*)&tw[code][f4 * 4] =
                *(const float4*)(wg + (size_t)(c0 + code) * D_DIM + f4 * 4);
        }
        __syncthreads();
        const int j = tid & 31, dg = tid >> 5;  // dg 0..7
        #pragma unroll
        for (int dd = 0; dd < 32; ++dd) {
            int d = dd * 8 + dg;
            wt[(size_t)d * K_CB + c0 + j] = tw[j][d];
        }
    }
}

// ---------------- K2: MFMA distance — 32 rows/wave, DOUBLE-BUFFERED staging ----------------
// grid(512): block = 128 rows (4 waves x 32); 16 col-phases of 64 codes.
// R6 lesson: dur tracks latency-hiding, not work. Old {stage; barrier+drain;
// compute; barrier} exposed L2 latency serially every phase. New m97-style
// 2-phase: {stage NEXT into buf^1; compute buf; barrier} — the vmcnt(0) drain
// at the barrier covers loads issued BEFORE a full compute phase.
__global__ __launch_bounds__(256, 2) void k_dist(
        const float* __restrict__ eg, const unsigned short* __restrict__ wfrag,
        const float* __restrict__ wn,
        int* __restrict__ idx_ws, int* __restrict__ fixlist, int* __restrict__ fixcnt) {
    __shared__ __align__(16) unsigned short Bs[2][32 * BLINE];   // 66.5 KB
    __shared__ float wnS[K_CB];
    const int tid  = threadIdx.x;
    const int lane = tid & 63;
    const int wv   = tid >> 6;
    const int q    = lane >> 4;
    const int m15  = lane & 15;
    const int waveRow = blockIdx.x * 128 + wv * 32;

    // ---- wn -> LDS once (published by prologue barrier) ----
    #pragma unroll
    for (int i = 0; i < 4; ++i) wnS[tid + i * 256] = wn[tid + i * 256];

    // ---- A fragments: bf16-hi only, 2 row-tiles, kept in regs whole kernel ----
    short8 afh0[8], afh1[8];
    #pragma unroll
    for (int mt = 0; mt < 2; ++mt) {
        const float* rowp = eg + (size_t)(waveRow + mt * 16 + m15) * D_DIM + q * 8;
        #pragma unroll
        for (int win = 0; win < 8; ++win) {
            const float4* pa = (const float4*)(rowp + win * 32);
            float4 x0 = pa[0], x1 = pa[1];
            const float a[8] = {x0.x, x0.y, x0.z, x0.w, x1.x, x1.y, x1.z, x1.w};
            short8 h;
            #pragma unroll
            for (int i = 0; i < 8; ++i) h[i] = (short)bf16_rne(a[i]);
            if (mt == 0) afh0[win] = h; else afh1[win] = h;
        }
    }

    float best[8], sec[8];
    int bidx[8];
    #pragma unroll
    for (int s = 0; s < 8; ++s) { best[s] = 3.4e38f; sec[s] = 3.4e38f; bidx[s] = 0; }

    // ---- prologue: stage phase 0 into buf 0 ----
    #pragma unroll
    for (int t = 0; t < 8; ++t) {
        int L = wv * 8 + t;
        const unsigned short* src = wfrag + ((size_t)L * 1024) * 8 + lane * 8;
        __builtin_amdgcn_global_load_lds(
            (const __attribute__((address_space(1))) unsigned int*)src,
            (__attribute__((address_space(3))) unsigned int*)&Bs[0][L * BLINE],
            16, 0, 0);
    }
    __syncthreads();   // drains prologue stage; publishes wnS

    for (int cb = 0; cb < 16; ++cb) {
        const int p = cb & 1;
        // ---- stage NEXT phase into the other buffer (latency hides under compute) ----
        if (cb < 15) {
            #pragma unroll
            for (int t = 0; t < 8; ++t) {
                int L = wv * 8 + t;
                const unsigned short* src =
                    wfrag + ((size_t)L * 1024 + (cb + 1) * 64) * 8 + lane * 8;
                __builtin_amdgcn_global_load_lds(
                    (const __attribute__((address_space(1))) unsigned int*)src,
                    (__attribute__((address_space(3))) unsigned int*)&Bs[p ^ 1][L * BLINE],
                    16, 0, 0);
            }
        }
        // ---- compute current buffer ----
        #pragma unroll
        for (int nt = 0; nt < 4; ++nt) {
            floatx4 acc0 = (floatx4){0.f, 0.f, 0.f, 0.f};
            floatx4 acc1 = (floatx4){0.f, 0.f, 0.f, 0.f};
            #pragma unroll
            for (int win = 0; win < 8; ++win) {
                int kc = win * 4 + q;
                short8 bfh = *(short8*)&Bs[p][kc * BLINE + (nt * 16 + m15) * 8];
                acc0 = __builtin_amdgcn_mfma_f32_16x16x32_bf16(afh0[win], bfh, acc0, 0, 0, 0);
                acc1 = __builtin_amdgcn_mfma_f32_16x16x32_bf16(afh1[win], bfh, acc1, 0, 0, 0);
            }
            int col = cb * 64 + nt * 16 + m15;
            float Ck = wnS[col];
            #pragma unroll
            for (int reg = 0; reg < 4; ++reg) {
                float d0 = __builtin_fmaf(-2.0f, acc0[reg], Ck);
                bool lt0 = d0 < best[reg];
                sec[reg]  = __builtin_amdgcn_fmed3f(d0, best[reg], sec[reg]);
                best[reg] = fminf(d0, best[reg]);
                bidx[reg] = lt0 ? col : bidx[reg];
                float d1 = __builtin_fmaf(-2.0f, acc1[reg], Ck);
                int s1 = 4 + reg;
                bool lt1 = d1 < best[s1];
                sec[s1]  = __builtin_amdgcn_fmed3f(d1, best[s1], sec[s1]);
                best[s1] = fminf(d1, best[s1]);
                bidx[s1] = lt1 ? col : bidx[s1];
            }
        }
        __syncthreads();   // next-phase stage landed; buf p free for reuse
    }

    // butterfly top-2 merge across the 16 m15 lanes (rows live per (q,mt,reg))
    #pragma unroll
    for (int s = 0; s < 8; ++s) {
        float b = best[s], se = sec[s];
        int ix = bidx[s];
        #pragma unroll
        for (int m = 1; m < 16; m <<= 1) {
            float bo = __shfl_xor(b, m, 64);
            float so = __shfl_xor(se, m, 64);
            int   io = __shfl_xor(ix, m, 64);
            float ns = fminf(fminf(se, so), fmaxf(b, bo));
            if (bo < b || (bo == b && io < ix)) { b = bo; ix = io; }
            se = ns;
        }
        if (m15 == 0) {
            int row = waveRow + (s >> 2) * 16 + q * 4 + (s & 3);
            idx_ws[row] = ix;
            if (se - b < TAU) {
                int p = atomicAdd(fixcnt, 1);
                fixlist[p] = row;
            }
        }
    }
}

// ---------------- K3: recheck — fp32-chain sweep + fp64 verify of top-2 ----------------
// np_dist quantizes distances to a 3.05e-5 grid (d~256, ulp 2^-15); fp32-chain
// m error ~1e-8 can never displace a code by a full grid step, so the true
// argmin is always within each wave's approx top-2. fp64-verify those two
// (wave-parallel), atomicMin the verified key. Same grid values + lowest-idx
// tie-break as the full-fp64 sweep at half the FMA issue cost.
#define FG_ROWS 8
__global__ __launch_bounds__(256) void k_fixup(
        const float* __restrict__ eg, const float* __restrict__ wg,
        const float* __restrict__ wt, const float* __restrict__ wnorm,
        const int* __restrict__ fixlist, const int* __restrict__ fixcnt,
        unsigned long long* __restrict__ keys) {
    __shared__ __align__(16) float xs[FG_ROWS][D_DIM];   // 8 KB
    __shared__ float AnS[FG_ROWS];
    const int tid  = threadIdx.x;
    const int lane = tid & 63;
    const int cnt = *fixcnt;
    if (cnt == 0) return;
    const int ngroups = (cnt + FG_ROWS - 1) / FG_ROWS;
    const int ntiles  = ngroups * 2;
    const int rowg = tid >> 7;               // 0,1 -> rows 4*rowg..4*rowg+3
    const int cg   = tid & 127;              // code group (4 codes each)
    for (int t = blockIdx.x; t < ntiles; t += gridDim.x) {
        const int g     = t >> 1;
        const int chunk = t & 1;
        __syncthreads();   // xs/AnS reuse guard across grid-stride tiles
        int rows[FG_ROWS];
        #pragma unroll
        for (int i = 0; i < FG_ROWS; ++i) {
            int j = g * FG_ROWS + i;
            rows[i] = fixlist[j < cnt ? j : cnt - 1];
        }
        #pragma unroll
        for (int i = 0; i < FG_ROWS; ++i)
            xs[i][tid] = eg[(size_t)rows[i] * D_DIM + tid];
        __syncthreads();

        // ---- row norms from LDS copy (numpy-pairwise-exact) ----
        if (tid < 16) {
            int row = tid >> 1, half = tid & 1;
            float sN = pw128_sq((const float4*)&xs[row][half * 128]);
            float so = __shfl_xor(sN, 1, 64);
            if (half == 0) AnS[row] = sN + so;
        }

        const int c0 = chunk * 512 + cg * 4;
        float Cw[4];
        #pragma unroll
        for (int c = 0; c < 4; ++c) Cw[c] = wnorm[c0 + c];

        float s[4][4];
        #pragma unroll
        for (int r = 0; r < 4; ++r)
            #pragma unroll
            for (int c = 0; c < 4; ++c) s[r][c] = 0.f;

        #pragma unroll 2
        for (int d = 0; d < D_DIM; d += 2) {
            float4 wa = *(const float4*)(wt + (size_t)d * K_CB + c0);
            float4 wb = *(const float4*)(wt + (size_t)(d + 1) * K_CB + c0);
            #pragma unroll
            for (int r = 0; r < 4; ++r) {
                float2 e2 = *(const float2*)&xs[rowg * 4 + r][d];
                s[r][0] += e2.x * wa.x + e2.y * wb.x;
                s[r][1] += e2.x * wa.y + e2.y * wb.y;
                s[r][2] += e2.x * wa.z + e2.y * wb.z;
                s[r][3] += e2.x * wa.w + e2.y * wb.w;
            }
        }
        __syncthreads();   // AnS ready for all threads

        #pragma unroll
        for (int r = 0; r < 4; ++r) {
            const int R = rowg * 4 + r;
            float An = AnS[R];
            // thread-local top-2 keys over its 4 codes
            unsigned long long kb = 0xFFFFFFFFFFFFFFFFull, ks = 0xFFFFFFFFFFFFFFFFull;
            #pragma unroll
            for (int c = 0; c < 4; ++c) {
                float dq = np_dist(An, s[r][c], Cw[c]);
                unsigned long long kk = dist_key(dq, c0 + c);
                if (kk < kb) { ks = kb; kb = kk; }
                else if (kk < ks) { ks = kk; }
            }
            // wave butterfly top-2 merge (lexicographic on (gridval, idx))
            #pragma unroll
            for (int m = 1; m < 64; m <<= 1) {
                unsigned long long ko = __shfl_xor(kb, m, 64);
                unsigned long long so = __shfl_xor(ks, m, 64);
                if (ko < kb) { ks = (so < kb) ? so : kb; kb = ko; }
                else         { ks = (ko < ks) ? ko : ks; }
            }
            // fp64 verify of the two candidates, wave-parallel (32 lanes each)
            int cand = (int)((lane < 32 ? kb : ks) & 0xFFFFFFFFull);
            const float* wrow = wg + (size_t)cand * D_DIM + (lane & 31) * 8;
            const float* erow = &xs[R][(lane & 31) * 8];
            double sm = 0.0;
            #pragma unroll
            for (int jj = 0; jj < 8; ++jj)
                sm += (double)erow[jj] * (double)wrow[jj];
            #pragma unroll
            for (int m = 1; m < 32; m <<= 1) sm += __shfl_xor(sm, m, 64);
            double smo = __shfl_xor(sm, 32, 64);
            if (lane == 0) {
                int i0 = (int)(kb & 0xFFFFFFFFull);
                int i1 = (int)(ks & 0xFFFFFFFFull);
                float d0 = np_dist(An, (float)sm,  wnorm[i0]);
                float d1 = np_dist(An, (float)smo, wnorm[i1]);
                unsigned long long k0 = dist_key(d0, i0);
                unsigned long long k1 = dist_key(d1, i1);
                unsigned long long kf = k0 < k1 ? k0 : k1;
                int j = g * FG_ROWS + R;
                if (j < cnt) atomicMin(&keys[j], kf);
            }
        }
    }
}

// ---------------- K3b: scatter fixup winners back into idx_ws ----------------
__global__ void k_fixscatter(const int* __restrict__ fixlist, const int* __restrict__ fixcnt,
                             const unsigned long long* __restrict__ keys,
                             int* __restrict__ idx_ws) {
    const int cnt = *fixcnt;
    for (int j = blockIdx.x * blockDim.x + threadIdx.x; j < cnt;
         j += gridDim.x * blockDim.x)
        idx_ws[fixlist[j]] = (int)(keys[j] & 0xFFFFFFFFull);
}

// ---------------- K4: gather + STE + loss partials + histogram (float4 vectorized) ----------------
__global__ void k_final(const float* __restrict__ eg, const float* __restrict__ wg,
                        const int* __restrict__ idx_ws, float* __restrict__ qout,
                        float* __restrict__ iout, int* __restrict__ hist,
                        double* __restrict__ partials) {
    const int tid  = threadIdx.x;
    const int sub  = tid >> 6;      // 0..3: row within quad
    const int lane = tid & 63;      // float4 column
    const int rowBase = blockIdx.x * 16;
    double acc = 0.0;
    #pragma unroll
    for (int g = 0; g < 4; ++g) {
        int row = rowBase + g * 4 + sub;
        int k = idx_ws[row];
        float4 ev = ((const float4*)(eg + (size_t)row * D_DIM))[lane];
        float4 wv = ((const float4*)(wg + (size_t)k   * D_DIM))[lane];
        float dx = wv.x - ev.x, dy = wv.y - ev.y, dz = wv.z - ev.z, dw = wv.w - ev.w;
        float4 qv = {ev.x + dx, ev.y + dy, ev.z + dz, ev.w + dw};
        ((float4*)(qout + (size_t)row * D_DIM))[lane] = qv;
        acc += (double)(dx * dx) + (double)(dy * dy)
             + (double)(dz * dz) + (double)(dw * dw);
        if (lane == 0) {
            iout[row] = (float)k;
            atomicAdd(&hist[k], 1);
        }
    }
    __shared__ double red[256];
    red[tid] = acc;
    __syncthreads();
    for (int st = 128; st > 0; st >>= 1) {
        if (tid < st) red[tid] += red[tid + st];
        __syncthreads();
    }
    if (tid == 0) partials[blockIdx.x] = red[0];
}

// ---------------- K5: scalars ----------------
__global__ void k_scalars(const int* __restrict__ hist, const double* __restrict__ partials,
                          float* __restrict__ sout) {
    const int tid = threadIdx.x;
    double s = 0.0;
    for (int j = tid; j < N_ROWS / 16; j += 256) s += partials[j];
    int m = 0;
    for (int j = tid; j < K_CB; j += 256) m = max(m, hist[j]);
    __shared__ double rs[256];
    __shared__ int    rm[256];
    rs[tid] = s; rm[tid] = m;
    __syncthreads();
    for (int st = 128; st > 0; st >>= 1) {
        if (tid < st) { rs[tid] += rs[tid + st]; rm[tid] = max(rm[tid], rm[tid + st]); }
        __syncthreads();
    }
    if (tid == 0) {
        sout[0] = (float)(rs[0] / (double)((size_t)N_ROWS * D_DIM));
        sout[1] = (float)rm[0] / 65536.0f;
    }
}

extern "C" void kernel_launch(void* const* d_in, const int* in_sizes, int n_in,
                              void* d_out, int out_size, void* d_ws, size_t ws_size,
                              hipStream_t stream) {
    const float* e = (const float*)d_in[0];
    const float* w = (const float*)d_in[1];
    float* out  = (float*)d_out;
    float* qout = out;
    float* iout = out + (size_t)N_ROWS * D_DIM;
    float* sout = iout + N_ROWS;

    char* ws = (char*)d_ws;
    float*  wn       = (float*) (ws + OFF_WN);
    int*    fixcnt   = (int*)   (ws + OFF_FIXCNT);
    int*    hist     = (int*)   (ws + OFF_HIST);
    int*    idxp     = (int*)   (ws + OFF_IDX);
    int*    list     = (int*)   (ws + OFF_LIST);
    double* partials = (double*)(ws + OFF_PART);
    unsigned short* wfrag = (unsigned short*)(ws + OFF_WFRAG);
    unsigned long long* keys = (unsigned long long*)(ws + OFF_KEYS);
    float*  wt       = (float*) (ws + OFF_WT);

    hipMemsetAsync(ws + OFF_FIXCNT, 0, 4352, stream);        // fixcnt + hist
    hipMemsetAsync(ws + OFF_KEYS, 0xFF, 524288, stream);     // keys = u64 max

    hipLaunchKernelGGL(k_prep,       dim3(164),         dim3(256), 0, stream, w, wn, wfrag, wt);
    hipLaunchKernelGGL(k_dist,       dim3(512),         dim3(256), 0, stream, e, wfrag, wn, idxp, list, fixcnt);
    hipLaunchKernelGGL(k_fixup,      dim3(2048),        dim3(256), 0, stream, e, w, wt, wn, list, fixcnt, keys);
    hipLaunchKernelGGL(k_fixscatter, dim3(64),          dim3(256), 0, stream, list, fixcnt, keys, idxp);
    hipLaunchKernelGGL(k_final,      dim3(N_ROWS / 16), dim3(256), 0, stream, e, w, idxp, qout, iout, hist, partials);
    hipLaunchKernelGGL(k_scalars,    dim3(1),           dim3(256), 0, stream, hist, partials, sout);
}

// Round 8
// 295.895 us; speedup vs baseline: 1.3544x; 1.0035x over previous
//
#include <hip/hip_runtime.h>

typedef __attribute__((ext_vector_type(8))) short short8;
typedef __attribute__((ext_vector_type(4))) float floatx4;

#define N_ROWS 65536
#define K_CB   1024
#define D_DIM  256

// single-term distance (ah*bh): residual terms dropped; error folded into the
// recheck band (R6/R7-proven numerics, absmax 0.0).
#define TAU 4.0e-4f
#define BLINE 520   // shorts per B LDS line (512 data + 8 pad = 1040 B)
#define PRS 260     // floats per staged e-row (256 data + 4 pad; 4-bank stagger)

// ws layout (bytes) — ws_size >= 14 MB proven on this harness
#define OFF_WN     262144    // float[1024]
#define OFF_FIXCNT 266240    // int
#define OFF_HIST   266496    // int[1024]
#define OFF_IDX    270592    // int[65536]
#define OFF_LIST   532736    // int[65536]
#define OFF_PART   794880    // double[4096]
#define OFF_WFRAG  827392    // ushort[32*1024*8] = 512 KB (hi fragments only)
#define OFF_KEYS   1351680   // u64[65536] = 512 KB (fixup argmin keys)
#define OFF_WT     1875968   // float[256*1024] = 1 MB (W transposed [d][k])

// ---- numpy pairwise fp32 sum-of-squares emulation (contract off!) ----
__device__ __forceinline__ float pw128_sq(const float4* p) {
#pragma clang fp contract(off)
    float4 q0 = p[0], q1 = p[1];
    float r0 = q0.x * q0.x, r1 = q0.y * q0.y, r2 = q0.z * q0.z, r3 = q0.w * q0.w;
    float r4 = q1.x * q1.x, r5 = q1.y * q1.y, r6 = q1.z * q1.z, r7 = q1.w * q1.w;
    for (int i = 1; i < 16; ++i) {
        float4 u0 = p[2 * i], u1 = p[2 * i + 1];
        r0 = r0 + u0.x * u0.x; r1 = r1 + u0.y * u0.y;
        r2 = r2 + u0.z * u0.z; r3 = r3 + u0.w * u0.w;
        r4 = r4 + u1.x * u1.x; r5 = r5 + u1.y * u1.y;
        r6 = r6 + u1.z * u1.z; r7 = r7 + u1.w * u1.w;
    }
    return ((r0 + r1) + (r2 + r3)) + ((r4 + r5) + (r6 + r7));
}
__device__ __forceinline__ float rownorm_np(const float* row) {
#pragma clang fp contract(off)
    float s0 = pw128_sq((const float4*)row);
    float s1 = pw128_sq((const float4*)(row + 128));
    return s0 + s1;
}
__device__ __forceinline__ float np_dist(float A, float m, float Ck) {
#pragma clang fp contract(off)
    float Bv = 2.0f * m;
    float t  = A - Bv;
    return t + Ck;
}
__device__ __forceinline__ unsigned short bf16_rne(float x) {
    unsigned u = __float_as_uint(x);
    unsigned r = u + 0x7fff + ((u >> 16) & 1);
    return (unsigned short)(r >> 16);
}
__device__ __forceinline__ unsigned long long dist_key(float d, int idx) {
    unsigned u = __float_as_uint(d);
    unsigned k32 = u ^ (((unsigned)((int)u >> 31)) | 0x80000000u);
    return ((unsigned long long)k32 << 32) | (unsigned)idx;
}

// ---------------- K1: prep — w-norms + wfrag + wT ----------------
__global__ __launch_bounds__(256) void k_prep(
        const float* __restrict__ wg,
        float* __restrict__ wn,
        unsigned short* __restrict__ wfrag, float* __restrict__ wt) {
    __shared__ __align__(16) float es[32 * PRS];
    const int tid = threadIdx.x;
    const int bx  = blockIdx.x;
    if (bx < 4) {
        int row = bx * 256 + tid;
        wn[row] = rownorm_np(wg + (size_t)row * D_DIM);
    } else if (bx < 132) {
        // ---- wfrag: bf16-hi fragments only, layout [kc][col][8] ----
        int t = (bx - 4) * 256 + tid;        // 0..32767
        int col = t >> 5, kc = t & 31;
        const float4* src = (const float4*)(wg + (size_t)col * D_DIM + kc * 8);
        float4 v0 = src[0], v1 = src[1];
        const float a[8] = {v0.x, v0.y, v0.z, v0.w, v1.x, v1.y, v1.z, v1.w};
        short8 h;
        #pragma unroll
        for (int i = 0; i < 8; ++i) h[i] = (short)bf16_rne(a[i]);
        *(short8*)(wfrag + ((size_t)kc * 1024 + col) * 8) = h;
    } else {
        // ---- wT: float transpose [d][k], 32 codes per block via LDS ----
        float (*tw)[PRS] = (float(*)[PRS])es;   // [32][260]
        const int cb = bx - 132;                // 0..31
        const int c0 = cb * 32;
        #pragma unroll
        for (int it = 0; it < 8; ++it) {
            int idx = it * 256 + tid;           // float4 index
            int code = idx >> 6, f4 = idx & 63;
            *(float4*)&tw[code][f4 * 4] =
                *(const float4*)(wg + (size_t)(c0 + code) * D_DIM + f4 * 4);
        }
        __syncthreads();
        const int j = tid & 31, dg = tid >> 5;  // dg 0..7
        #pragma unroll
        for (int dd = 0; dd < 32; ++dd) {
            int d = dd * 8 + dg;
            wt[(size_t)d * K_CB + c0 + j] = tw[j][d];
        }
    }
}

// ---------------- K2: MFMA distance — coalesced e-prologue + dbuf staging ----------------
// grid(512): block = 128 rows (4 waves x 32); 16 col-phases of 64 codes.
// R7 lesson: the wall was the A-fragment prologue's full-wave scatter (each
// load touched 64 distinct 16B segments) paid by all 512 co-resident blocks
// at t=0. Fix: stage e rows through LDS with global_load_lds (coalesced 1KB
// rows, HW-native base+lane*16 dest), then ds_read fragments (PRS stride ->
// 2-way conflicts, free). Also: win-outer/nt-inner = 8 independent MFMA
// chains (was 2) -> latency-pipelined.
__global__ __launch_bounds__(256, 2) void k_dist(
        const float* __restrict__ eg, const unsigned short* __restrict__ wfrag,
        const float* __restrict__ wn,
        int* __restrict__ idx_ws, int* __restrict__ fixlist, int* __restrict__ fixcnt) {
    __shared__ __align__(16) unsigned short Bs[2][32 * BLINE];   // 66.56 KB
    __shared__ float wnS[K_CB];
    const int tid  = threadIdx.x;
    const int lane = tid & 63;
    const int wv   = tid >> 6;
    const int q    = lane >> 4;
    const int m15  = lane & 15;
    const int waveRow = blockIdx.x * 128 + wv * 32;

    // ---- wn -> LDS once (published by first prologue barrier) ----
    #pragma unroll
    for (int i = 0; i < 4; ++i) wnS[tid + i * 256] = wn[tid + i * 256];

    // ---- A fragments via coalesced LDS round-trip (Bs reused as [64][PRS] f32) ----
    float* ef = (float*)&Bs[0][0];           // 64*260*4 = 66560 B = sizeof(Bs)
    short8 afh0[8], afh1[8];
    #pragma unroll
    for (int mt = 0; mt < 2; ++mt) {
        #pragma unroll
        for (int t = 0; t < 16; ++t) {
            int slot = wv * 16 + t;          // wave-uniform LDS base
            const float* src = eg + (size_t)(waveRow + mt * 16 + t) * D_DIM + lane * 4;
            __builtin_amdgcn_global_load_lds(
                (const __attribute__((address_space(1))) unsigned int*)src,
                (__attribute__((address_space(3))) unsigned int*)&ef[slot * PRS],
                16, 0, 0);
        }
        __syncthreads();   // drain stage (also publishes wnS on mt=0)
        const float* rowp = &ef[(wv * 16 + m15) * PRS + q * 8];
        #pragma unroll
        for (int win = 0; win < 8; ++win) {
            float4 x0 = *(const float4*)(rowp + win * 32);
            float4 x1 = *(const float4*)(rowp + win * 32 + 4);
            const float a[8] = {x0.x, x0.y, x0.z, x0.w, x1.x, x1.y, x1.z, x1.w};
            short8 h;
            #pragma unroll
            for (int i = 0; i < 8; ++i) h[i] = (short)bf16_rne(a[i]);
            if (mt == 0) afh0[win] = h; else afh1[win] = h;
        }
        __syncthreads();   // fragments read; ef region free for reuse
    }

    float best[8], sec[8];
    int bidx[8];
    #pragma unroll
    for (int s = 0; s < 8; ++s) { best[s] = 3.4e38f; sec[s] = 3.4e38f; bidx[s] = 0; }

    // ---- prologue: stage phase 0 into buf 0 ----
    #pragma unroll
    for (int t = 0; t < 8; ++t) {
        int L = wv * 8 + t;
        const unsigned short* src = wfrag + ((size_t)L * 1024) * 8 + lane * 8;
        __builtin_amdgcn_global_load_lds(
            (const __attribute__((address_space(1))) unsigned int*)src,
            (__attribute__((address_space(3))) unsigned int*)&Bs[0][L * BLINE],
            16, 0, 0);
    }
    __syncthreads();

    for (int cb = 0; cb < 16; ++cb) {
        const int p = cb & 1;
        // ---- stage NEXT phase into the other buffer (hides under compute) ----
        if (cb < 15) {
            #pragma unroll
            for (int t = 0; t < 8; ++t) {
                int L = wv * 8 + t;
                const unsigned short* src =
                    wfrag + ((size_t)L * 1024 + (cb + 1) * 64) * 8 + lane * 8;
                __builtin_amdgcn_global_load_lds(
                    (const __attribute__((address_space(1))) unsigned int*)src,
                    (__attribute__((address_space(3))) unsigned int*)&Bs[p ^ 1][L * BLINE],
                    16, 0, 0);
            }
        }
        // ---- compute current buffer: win outer -> 8 independent acc chains ----
        floatx4 acc[2][4];
        #pragma unroll
        for (int mt = 0; mt < 2; ++mt)
            #pragma unroll
            for (int nt = 0; nt < 4; ++nt)
                acc[mt][nt] = (floatx4){0.f, 0.f, 0.f, 0.f};
        #pragma unroll
        for (int win = 0; win < 8; ++win) {
            int kc = win * 4 + q;
            #pragma unroll
            for (int nt = 0; nt < 4; ++nt) {
                short8 bfh = *(short8*)&Bs[p][kc * BLINE + (nt * 16 + m15) * 8];
                acc[0][nt] = __builtin_amdgcn_mfma_f32_16x16x32_bf16(afh0[win], bfh, acc[0][nt], 0, 0, 0);
                acc[1][nt] = __builtin_amdgcn_mfma_f32_16x16x32_bf16(afh1[win], bfh, acc[1][nt], 0, 0, 0);
            }
        }
        // ---- fold into running top-2 (cols ascend with cb,nt -> first-min kept) ----
        #pragma unroll
        for (int nt = 0; nt < 4; ++nt) {
            int col = cb * 64 + nt * 16 + m15;
            float Ck = wnS[col];
            #pragma unroll
            for (int reg = 0; reg < 4; ++reg) {
                float d0 = __builtin_fmaf(-2.0f, acc[0][nt][reg], Ck);
                bool lt0 = d0 < best[reg];
                sec[reg]  = __builtin_amdgcn_fmed3f(d0, best[reg], sec[reg]);
                best[reg] = fminf(d0, best[reg]);
                bidx[reg] = lt0 ? col : bidx[reg];
                float d1 = __builtin_fmaf(-2.0f, acc[1][nt][reg], Ck);
                int s1 = 4 + reg;
                bool lt1 = d1 < best[s1];
                sec[s1]  = __builtin_amdgcn_fmed3f(d1, best[s1], sec[s1]);
                best[s1] = fminf(d1, best[s1]);
                bidx[s1] = lt1 ? col : bidx[s1];
            }
        }
        __syncthreads();   // next-phase stage landed; buf p free for reuse
    }

    // butterfly top-2 merge across the 16 m15 lanes (rows live per (q,mt,reg))
    #pragma unroll
    for (int s = 0; s < 8; ++s) {
        float b = best[s], se = sec[s];
        int ix = bidx[s];
        #pragma unroll
        for (int m = 1; m < 16; m <<= 1) {
            float bo = __shfl_xor(b, m, 64);
            float so = __shfl_xor(se, m, 64);
            int   io = __shfl_xor(ix, m, 64);
            float ns = fminf(fminf(se, so), fmaxf(b, bo));
            if (bo < b || (bo == b && io < ix)) { b = bo; ix = io; }
            se = ns;
        }
        if (m15 == 0) {
            int row = waveRow + (s >> 2) * 16 + q * 4 + (s & 3);
            idx_ws[row] = ix;
            if (se - b < TAU) {
                int p = atomicAdd(fixcnt, 1);
                fixlist[p] = row;
            }
        }
    }
}

// ---------------- K3: recheck — fp32-chain sweep + fp64 verify of top-2 ----------------
// np_dist quantizes distances to a 3.05e-5 grid (d~256, ulp 2^-15); fp32-chain
// m error ~1e-8 can never displace a code by a full grid step, so the true
// argmin is always within each wave's approx top-2. fp64-verify those two
// (wave-parallel), atomicMin the verified key.
#define FG_ROWS 8
__global__ __launch_bounds__(256) void k_fixup(
        const float* __restrict__ eg, const float* __restrict__ wg,
        const float* __restrict__ wt, const float* __restrict__ wnorm,
        const int* __restrict__ fixlist, const int* __restrict__ fixcnt,
        unsigned long long* __restrict__ keys) {
    __shared__ __align__(16) float xs[FG_ROWS][D_DIM];   // 8 KB
    __shared__ float AnS[FG_ROWS];
    const int tid  = threadIdx.x;
    const int lane = tid & 63;
    const int cnt = *fixcnt;
    if (cnt == 0) return;
    const int ngroups = (cnt + FG_ROWS - 1) / FG_ROWS;
    const int ntiles  = ngroups * 2;
    const int rowg = tid >> 7;               // 0,1 -> rows 4*rowg..4*rowg+3
    const int cg   = tid & 127;              // code group (4 codes each)
    for (int t = blockIdx.x; t < ntiles; t += gridDim.x) {
        const int g     = t >> 1;
        const int chunk = t & 1;
        __syncthreads();   // xs/AnS reuse guard across grid-stride tiles
        int rows[FG_ROWS];
        #pragma unroll
        for (int i = 0; i < FG_ROWS; ++i) {
            int j = g * FG_ROWS + i;
            rows[i] = fixlist[j < cnt ? j : cnt - 1];
        }
        #pragma unroll
        for (int i = 0; i < FG_ROWS; ++i)
            xs[i][tid] = eg[(size_t)rows[i] * D_DIM + tid];
        __syncthreads();

        // ---- row norms from LDS copy (numpy-pairwise-exact) ----
        if (tid < 16) {
            int row = tid >> 1, half = tid & 1;
            float sN = pw128_sq((const float4*)&xs[row][half * 128]);
            float so = __shfl_xor(sN, 1, 64);
            if (half == 0) AnS[row] = sN + so;
        }

        const int c0 = chunk * 512 + cg * 4;
        float Cw[4];
        #pragma unroll
        for (int c = 0; c < 4; ++c) Cw[c] = wnorm[c0 + c];

        float s[4][4];
        #pragma unroll
        for (int r = 0; r < 4; ++r)
            #pragma unroll
            for (int c = 0; c < 4; ++c) s[r][c] = 0.f;

        #pragma unroll 2
        for (int d = 0; d < D_DIM; d += 2) {
            float4 wa = *(const float4*)(wt + (size_t)d * K_CB + c0);
            float4 wb = *(const float4*)(wt + (size_t)(d + 1) * K_CB + c0);
            #pragma unroll
            for (int r = 0; r < 4; ++r) {
                float2 e2 = *(const float2*)&xs[rowg * 4 + r][d];
                s[r][0] += e2.x * wa.x + e2.y * wb.x;
                s[r][1] += e2.x * wa.y + e2.y * wb.y;
                s[r][2] += e2.x * wa.z + e2.y * wb.z;
                s[r][3] += e2.x * wa.w + e2.y * wb.w;
            }
        }
        __syncthreads();   // AnS ready for all threads

        #pragma unroll
        for (int r = 0; r < 4; ++r) {
            const int R = rowg * 4 + r;
            float An = AnS[R];
            unsigned long long kb = 0xFFFFFFFFFFFFFFFFull, ks = 0xFFFFFFFFFFFFFFFFull;
            #pragma unroll
            for (int c = 0; c < 4; ++c) {
                float dq = np_dist(An, s[r][c], Cw[c]);
                unsigned long long kk = dist_key(dq, c0 + c);
                if (kk < kb) { ks = kb; kb = kk; }
                else if (kk < ks) { ks = kk; }
            }
            #pragma unroll
            for (int m = 1; m < 64; m <<= 1) {
                unsigned long long ko = __shfl_xor(kb, m, 64);
                unsigned long long so = __shfl_xor(ks, m, 64);
                if (ko < kb) { ks = (so < kb) ? so : kb; kb = ko; }
                else         { ks = (ko < ks) ? ko : ks; }
            }
            int cand = (int)((lane < 32 ? kb : ks) & 0xFFFFFFFFull);
            const float* wrow = wg + (size_t)cand * D_DIM + (lane & 31) * 8;
            const float* erow = &xs[R][(lane & 31) * 8];
            double sm = 0.0;
            #pragma unroll
            for (int jj = 0; jj < 8; ++jj)
                sm += (double)erow[jj] * (double)wrow[jj];
            #pragma unroll
            for (int m = 1; m < 32; m <<= 1) sm += __shfl_xor(sm, m, 64);
            double smo = __shfl_xor(sm, 32, 64);
            if (lane == 0) {
                int i0 = (int)(kb & 0xFFFFFFFFull);
                int i1 = (int)(ks & 0xFFFFFFFFull);
                float d0 = np_dist(An, (float)sm,  wnorm[i0]);
                float d1 = np_dist(An, (float)smo, wnorm[i1]);
                unsigned long long k0 = dist_key(d0, i0);
                unsigned long long k1 = dist_key(d1, i1);
                unsigned long long kf = k0 < k1 ? k0 : k1;
                int j = g * FG_ROWS + R;
                if (j < cnt) atomicMin(&keys[j], kf);
            }
        }
    }
}

// ---------------- K3b: scatter fixup winners back into idx_ws ----------------
__global__ void k_fixscatter(const int* __restrict__ fixlist, const int* __restrict__ fixcnt,
                             const unsigned long long* __restrict__ keys,
                             int* __restrict__ idx_ws) {
    const int cnt = *fixcnt;
    for (int j = blockIdx.x * blockDim.x + threadIdx.x; j < cnt;
         j += gridDim.x * blockDim.x)
        idx_ws[fixlist[j]] = (int)(keys[j] & 0xFFFFFFFFull);
}

// ---------------- K4: gather + STE + loss partials + histogram (float4 vectorized) ----------------
__global__ void k_final(const float* __restrict__ eg, const float* __restrict__ wg,
                        const int* __restrict__ idx_ws, float* __restrict__ qout,
                        float* __restrict__ iout, int* __restrict__ hist,
                        double* __restrict__ partials) {
    const int tid  = threadIdx.x;
    const int sub  = tid >> 6;      // 0..3: row within quad
    const int lane = tid & 63;      // float4 column
    const int rowBase = blockIdx.x * 16;
    double acc = 0.0;
    #pragma unroll
    for (int g = 0; g < 4; ++g) {
        int row = rowBase + g * 4 + sub;
        int k = idx_ws[row];
        float4 ev = ((const float4*)(eg + (size_t)row * D_DIM))[lane];
        float4 wv = ((const float4*)(wg + (size_t)k   * D_DIM))[lane];
        float dx = wv.x - ev.x, dy = wv.y - ev.y, dz = wv.z - ev.z, dw = wv.w - ev.w;
        float4 qv = {ev.x + dx, ev.y + dy, ev.z + dz, ev.w + dw};
        ((float4*)(qout + (size_t)row * D_DIM))[lane] = qv;
        acc += (double)(dx * dx) + (double)(dy * dy)
             + (double)(dz * dz) + (double)(dw * dw);
        if (lane == 0) {
            iout[row] = (float)k;
            atomicAdd(&hist[k], 1);
        }
    }
    __shared__ double red[256];
    red[tid] = acc;
    __syncthreads();
    for (int st = 128; st > 0; st >>= 1) {
        if (tid < st) red[tid] += red[tid + st];
        __syncthreads();
    }
    if (tid == 0) partials[blockIdx.x] = red[0];
}

// ---------------- K5: scalars ----------------
__global__ void k_scalars(const int* __restrict__ hist, const double* __restrict__ partials,
                          float* __restrict__ sout) {
    const int tid = threadIdx.x;
    double s = 0.0;
    for (int j = tid; j < N_ROWS / 16; j += 256) s += partials[j];
    int m = 0;
    for (int j = tid; j < K_CB; j += 256) m = max(m, hist[j]);
    __shared__ double rs[256];
    __shared__ int    rm[256];
    rs[tid] = s; rm[tid] = m;
    __syncthreads();
    for (int st = 128; st > 0; st >>= 1) {
        if (tid < st) { rs[tid] += rs[tid + st]; rm[tid] = max(rm[tid], rm[tid + st]); }
        __syncthreads();
    }
    if (tid == 0) {
        sout[0] = (float)(rs[0] / (double)((size_t)N_ROWS * D_DIM));
        sout[1] = (float)rm[0] / 65536.0f;
    }
}

extern "C" void kernel_launch(void* const* d_in, const int* in_sizes, int n_in,
                              void* d_out, int out_size, void* d_ws, size_t ws_size,
                              hipStream_t stream) {
    const float* e = (const float*)d_in[0];
    const float* w = (const float*)d_in[1];
    float* out  = (float*)d_out;
    float* qout = out;
    float* iout = out + (size_t)N_ROWS * D_DIM;
    float* sout = iout + N_ROWS;

    char* ws = (char*)d_ws;
    float*  wn       = (float*) (ws + OFF_WN);
    int*    fixcnt   = (int*)   (ws + OFF_FIXCNT);
    int*    hist     = (int*)   (ws + OFF_HIST);
    int*    idxp     = (int*)   (ws + OFF_IDX);
    int*    list     = (int*)   (ws + OFF_LIST);
    double* partials = (double*)(ws + OFF_PART);
    unsigned short* wfrag = (unsigned short*)(ws + OFF_WFRAG);
    unsigned long long* keys = (unsigned long long*)(ws + OFF_KEYS);
    float*  wt       = (float*) (ws + OFF_WT);

    hipMemsetAsync(ws + OFF_FIXCNT, 0, 4352, stream);        // fixcnt + hist
    hipMemsetAsync(ws + OFF_KEYS, 0xFF, 524288, stream);     // keys = u64 max

    hipLaunchKernelGGL(k_prep,       dim3(164),         dim3(256), 0, stream, w, wn, wfrag, wt);
    hipLaunchKernelGGL(k_dist,       dim3(512),         dim3(256), 0, stream, e, wfrag, wn, idxp, list, fixcnt);
    hipLaunchKernelGGL(k_fixup,      dim3(2048),        dim3(256), 0, stream, e, w, wt, wn, list, fixcnt, keys);
    hipLaunchKernelGGL(k_fixscatter, dim3(64),          dim3(256), 0, stream, list, fixcnt, keys, idxp);
    hipLaunchKernelGGL(k_final,      dim3(N_ROWS / 16), dim3(256), 0, stream, e, w, idxp, qout, iout, hist, partials);
    hipLaunchKernelGGL(k_scalars,    dim3(1),           dim3(256), 0, stream, hist, partials, sout);
}